// Round 3
// baseline (8597.671 us; speedup 1.0000x reference)
//
#include <hip/hip_runtime.h>
#include <math.h>

#define NN 100000
#define NE 3200000

static constexpr int TPB = 256;
static constexpr int GRID_E = (NE + TPB - 1) / TPB;   // 12500
static constexpr int GRID_N = (NN + TPB - 1) / TPB;   // 391

// ---------------- init small state ----------------
__global__ void k_init(const int* __restrict__ kptr, unsigned* __restrict__ prefix,
                       int* __restrict__ target, int* __restrict__ cgt,
                       double* __restrict__ stats) {
  *prefix = 0u;
  *target = *kptr;   // rank (1-indexed) of the k-th largest in desc-key ascending order
  *cgt = 0;
  stats[0] = 0.0;
  stats[1] = 0.0;
}

// ---------------- edge preprocessing ----------------
__global__ void k_deg(const int* __restrict__ dst, const float* __restrict__ ea,
                      float* __restrict__ deg) {
  int e = blockIdx.x * TPB + threadIdx.x;
  if (e >= NE) return;
  atomicAdd(&deg[dst[e]], fabsf(ea[e]));
}

__global__ void k_dinv(float* __restrict__ deg) {
  int n = blockIdx.x * TPB + threadIdx.x;
  if (n >= NN) return;
  float dg = deg[n];
  deg[n] = (dg > 0.0f) ? (1.0f / sqrtf(dg)) : 0.0f;
}

__global__ void k_norm(const int* __restrict__ src, const int* __restrict__ dst,
                       const float* __restrict__ ea, const float* __restrict__ dinv,
                       float* __restrict__ norm) {
  int e = blockIdx.x * TPB + threadIdx.x;
  if (e >= NE) return;
  norm[e] = dinv[src[e]] * fabsf(ea[e]) * dinv[dst[e]];
}

// ---------------- propagation ----------------
__global__ void k_prop1(const int* __restrict__ src, const int* __restrict__ dst,
                        const float* __restrict__ norm, const float* __restrict__ hin,
                        float* __restrict__ hout) {
  int e = blockIdx.x * TPB + threadIdx.x;
  if (e >= NE) return;
  atomicAdd(&hout[dst[e]], norm[e] * hin[src[e]]);
}

__global__ void k_prop8(const int* __restrict__ src, const int* __restrict__ dst,
                        const float* __restrict__ norm, const float* __restrict__ hin,
                        float* __restrict__ hout) {
  int e = blockIdx.x * TPB + threadIdx.x;
  if (e >= NE) return;
  int s = src[e], d = dst[e];
  float nv = norm[e];
  const float4* hp = (const float4*)(hin + (size_t)s * 8);
  float4 a = hp[0], b = hp[1];
  float* op = hout + (size_t)d * 8;
  atomicAdd(op + 0, nv * a.x);
  atomicAdd(op + 1, nv * a.y);
  atomicAdd(op + 2, nv * a.z);
  atomicAdd(op + 3, nv * a.w);
  atomicAdd(op + 4, nv * b.x);
  atomicAdd(op + 5, nv * b.y);
  atomicAdd(op + 6, nv * b.z);
  atomicAdd(op + 7, nv * b.w);
}

// ---------------- dense combines ----------------
__global__ void k_combine1(const float* __restrict__ x, const float* __restrict__ p1,
                           const float* __restrict__ p2, const float* __restrict__ p3,
                           const float* __restrict__ W, const float* __restrict__ b,
                           float* __restrict__ out) {
  int n = blockIdx.x * TPB + threadIdx.x;
  if (n >= NN) return;
  float h0 = x[n], h1 = p1[n], h2 = p2[n], h3 = p3[n];
  float* op = out + (size_t)n * 8;
  #pragma unroll
  for (int j = 0; j < 8; ++j) {
    float v = b[j] + h0 * W[j] + h1 * W[8 + j] + h2 * W[16 + j] + h3 * W[24 + j];
    op[j] = fmaxf(v, 0.0f);
  }
}

__global__ void k_combine8(const float* __restrict__ p0, const float* __restrict__ p1,
                           const float* __restrict__ p2, const float* __restrict__ p3,
                           const float* __restrict__ W, const float* __restrict__ b,
                           float* __restrict__ out) {
  int n = blockIdx.x * TPB + threadIdx.x;
  if (n >= NN) return;
  float h[4][8];
  {
    const float4* hp;
    hp = (const float4*)(p0 + (size_t)n * 8);
    float4 a = hp[0], c = hp[1];
    h[0][0]=a.x; h[0][1]=a.y; h[0][2]=a.z; h[0][3]=a.w; h[0][4]=c.x; h[0][5]=c.y; h[0][6]=c.z; h[0][7]=c.w;
    hp = (const float4*)(p1 + (size_t)n * 8);
    a = hp[0]; c = hp[1];
    h[1][0]=a.x; h[1][1]=a.y; h[1][2]=a.z; h[1][3]=a.w; h[1][4]=c.x; h[1][5]=c.y; h[1][6]=c.z; h[1][7]=c.w;
    hp = (const float4*)(p2 + (size_t)n * 8);
    a = hp[0]; c = hp[1];
    h[2][0]=a.x; h[2][1]=a.y; h[2][2]=a.z; h[2][3]=a.w; h[2][4]=c.x; h[2][5]=c.y; h[2][6]=c.z; h[2][7]=c.w;
    hp = (const float4*)(p3 + (size_t)n * 8);
    a = hp[0]; c = hp[1];
    h[3][0]=a.x; h[3][1]=a.y; h[3][2]=a.z; h[3][3]=a.w; h[3][4]=c.x; h[3][5]=c.y; h[3][6]=c.z; h[3][7]=c.w;
  }
  float* op = out + (size_t)n * 8;
  #pragma unroll
  for (int j = 0; j < 8; ++j) {
    float v = b[j];
    #pragma unroll
    for (int i = 0; i < 4; ++i) {
      #pragma unroll
      for (int f = 0; f < 8; ++f) v += h[i][f] * W[i * 64 + f * 8 + j];
    }
    op[j] = fmaxf(v, 0.0f);
  }
}

__global__ void k_combine3(const float* __restrict__ p0, const float* __restrict__ p1,
                           const float* __restrict__ p2, const float* __restrict__ p3,
                           const float* __restrict__ W, const float* __restrict__ b,
                           float* __restrict__ out) {
  int n = blockIdx.x * TPB + threadIdx.x;
  if (n >= NN) return;
  float v = b[0];
  const float* ps[4] = {p0, p1, p2, p3};
  #pragma unroll
  for (int i = 0; i < 4; ++i) {
    const float4* hp = (const float4*)(ps[i] + (size_t)n * 8);
    float4 a = hp[0], c = hp[1];
    v += a.x * W[i * 8 + 0] + a.y * W[i * 8 + 1] + a.z * W[i * 8 + 2] + a.w * W[i * 8 + 3];
    v += c.x * W[i * 8 + 4] + c.y * W[i * 8 + 5] + c.z * W[i * 8 + 6] + c.w * W[i * 8 + 7];
  }
  out[n] = fmaxf(v, 0.0f);
}

// ---------------- layernorm stats ----------------
__global__ void k_stats(const float* __restrict__ h, double* __restrict__ stats) {
  int n = blockIdx.x * TPB + threadIdx.x;
  float v = (n < NN) ? h[n] : 0.0f;
  double s = (double)v, s2 = (double)v * (double)v;
  #pragma unroll
  for (int o = 32; o > 0; o >>= 1) {
    s  += __shfl_down(s, o);
    s2 += __shfl_down(s2, o);
  }
  __shared__ double ls[4], ls2[4];
  int lane = threadIdx.x & 63, w = threadIdx.x >> 6;
  if (lane == 0) { ls[w] = s; ls2[w] = s2; }
  __syncthreads();
  if (threadIdx.x == 0) {
    atomicAdd(&stats[0], ls[0] + ls[1] + ls[2] + ls[3]);
    atomicAdd(&stats[1], ls2[0] + ls2[1] + ls2[2] + ls2[3]);
  }
}

__global__ void k_normkey(const float* __restrict__ h, const double* __restrict__ stats,
                          float* __restrict__ hn, unsigned* __restrict__ key) {
  int n = blockIdx.x * TPB + threadIdx.x;
  if (n >= NN) return;
  double mu = stats[0] / (double)NN;
  double var = stats[1] / (double)NN - mu * mu;
  if (var < 0.0) var = 0.0;
  double invs = 1.0 / sqrt(var + 1e-5);
  float v = (float)(((double)h[n] - mu) * invs);
  hn[n] = v;
  unsigned u = __float_as_uint(v);
  unsigned asc = (u & 0x80000000u) ? ~u : (u | 0x80000000u);  // ascending-order key
  key[n] = ~asc;                                              // descending-order key
}

// ---------------- radix select (k-th largest) ----------------
template <int SHIFT, unsigned MASK>
__global__ void k_hist(const unsigned* __restrict__ key, const unsigned* __restrict__ prefix,
                       unsigned* __restrict__ hist) {
  __shared__ unsigned lh[256];
  lh[threadIdx.x] = 0;
  __syncthreads();
  int n = blockIdx.x * TPB + threadIdx.x;
  unsigned pfx = *prefix;
  if (n < NN) {
    unsigned kk = key[n];
    if ((kk & MASK) == pfx) atomicAdd(&lh[(kk >> SHIFT) & 0xffu], 1u);
  }
  __syncthreads();
  if (lh[threadIdx.x]) atomicAdd(&hist[threadIdx.x], lh[threadIdx.x]);
}

template <int SHIFT>
__global__ void k_pick(const unsigned* __restrict__ hist, unsigned* __restrict__ prefix,
                       int* __restrict__ target) {
  int t = *target;
  unsigned cum = 0;
  for (int b = 0; b < 256; ++b) {
    unsigned c = hist[b];
    if ((int)(cum + c) >= t) {
      *prefix |= ((unsigned)b) << SHIFT;
      *target = t - (int)cum;
      return;
    }
    cum += c;
  }
}

// ---------------- stable top-k membership ----------------
__global__ void k_count(const unsigned* __restrict__ key, const unsigned* __restrict__ prefix,
                        int* __restrict__ partials, int* __restrict__ cgt) {
  int n = blockIdx.x * TPB + threadIdx.x;
  unsigned T = *prefix;
  bool eq = false, lt = false;
  if (n < NN) {
    unsigned kk = key[n];
    eq = (kk == T);
    lt = (kk < T);
  }
  unsigned long long meq = __ballot(eq);
  unsigned long long mlt = __ballot(lt);
  __shared__ int ce[4], cl[4];
  int lane = threadIdx.x & 63, w = threadIdx.x >> 6;
  if (lane == 0) { ce[w] = __popcll(meq); cl[w] = __popcll(mlt); }
  __syncthreads();
  if (threadIdx.x == 0) {
    partials[blockIdx.x] = ce[0] + ce[1] + ce[2] + ce[3];
    int l = cl[0] + cl[1] + cl[2] + cl[3];
    if (l) atomicAdd(cgt, l);
  }
}

__global__ void k_scan(const int* __restrict__ partials, int* __restrict__ offs,
                       const int* __restrict__ kptr, const int* __restrict__ cgt,
                       int* __restrict__ r) {
  if (threadIdx.x == 0) {
    int acc = 0;
    for (int b = 0; b < GRID_N; ++b) { offs[b] = acc; acc += partials[b]; }
    *r = *kptr - *cgt;   // how many ties (by ascending index) belong to top-k
  }
}

__global__ void k_final(const float* __restrict__ hn, const unsigned* __restrict__ key,
                        const unsigned* __restrict__ prefix, const int* __restrict__ offs,
                        const int* __restrict__ rptr, float* __restrict__ out) {
  int n = blockIdx.x * TPB + threadIdx.x;
  unsigned T = *prefix;
  int r = *rptr;
  bool eq = false, lt = false;
  float v = 0.0f;
  if (n < NN) {
    unsigned kk = key[n];
    eq = (kk == T);
    lt = (kk < T);
    v = hn[n];
  }
  unsigned long long m = __ballot(eq);
  __shared__ int wc[4];
  int lane = threadIdx.x & 63, w = threadIdx.x >> 6;
  if (lane == 0) wc[w] = __popcll(m);
  __syncthreads();
  int off = offs[blockIdx.x];
  for (int i = 0; i < w; ++i) off += wc[i];
  off += __popcll(m & ((1ull << lane) - 1ull));
  if (n >= NN) return;
  bool top = lt || (eq && off < r);
  unsigned asc = ~T;
  unsigned orig = (asc & 0x80000000u) ? (asc & 0x7fffffffu) : ~asc;
  float thr = fabsf(__uint_as_float(orig));   // k_smallest = |h at k-th largest|
  float tkv = top ? 1.0f : -1.0f;
  float z = v - thr + tkv * 0.1f;
  out[2 * n]     = v;
  out[2 * n + 1] = 1.0f / (1.0f + expf(-z));
}

// ---------------- host launch ----------------
extern "C" void kernel_launch(void* const* d_in, const int* in_sizes, int n_in,
                              void* d_out, int out_size, void* d_ws, size_t ws_size,
                              hipStream_t stream) {
  const float* x       = (const float*)d_in[0];
  const float* ea      = (const float*)d_in[1];
  const float* W1      = (const float*)d_in[2];
  const float* b1      = (const float*)d_in[3];
  const float* W2      = (const float*)d_in[4];
  const float* b2      = (const float*)d_in[5];
  const float* W3      = (const float*)d_in[6];
  const float* b3      = (const float*)d_in[7];
  const int* ei        = (const int*)d_in[8];   // int32 on device (harness converts int64)
  const int* kptr      = (const int*)d_in[9];
  float* out           = (float*)d_out;

  const int* src = ei;        // row 0
  const int* dst = ei + NE;   // row 1

  char* ws = (char*)d_ws;
  size_t off = 0;
  auto alloc = [&](size_t bytes) -> void* {
    void* p = ws + off;
    off += (bytes + 255) & ~(size_t)255;
    return p;
  };

  float*    norm     = (float*)alloc((size_t)NE * 4);
  float*    deg      = (float*)alloc((size_t)NN * 4);
  float*    pA       = (float*)alloc((size_t)NN * 8 * 4);
  float*    pB       = (float*)alloc((size_t)NN * 8 * 4);
  float*    pC       = (float*)alloc((size_t)NN * 8 * 4);
  float*    h1       = (float*)alloc((size_t)NN * 8 * 4);
  float*    h2       = (float*)alloc((size_t)NN * 8 * 4);
  float*    h3       = (float*)alloc((size_t)NN * 4);
  float*    hn       = (float*)alloc((size_t)NN * 4);
  unsigned* key      = (unsigned*)alloc((size_t)NN * 4);
  double*   stats    = (double*)alloc(2 * 8);
  unsigned* hist     = (unsigned*)alloc(256 * 4);
  int*      partials = (int*)alloc(512 * 4);
  int*      offs     = (int*)alloc(512 * 4);
  unsigned* prefix   = (unsigned*)alloc(4);
  int*      target   = (int*)alloc(4);
  int*      cgt      = (int*)alloc(4);
  int*      rr       = (int*)alloc(4);

  k_init<<<1, 1, 0, stream>>>(kptr, prefix, target, cgt, stats);

  hipMemsetAsync(deg, 0, (size_t)NN * 4, stream);
  k_deg<<<GRID_E, TPB, 0, stream>>>(dst, ea, deg);
  k_dinv<<<GRID_N, TPB, 0, stream>>>(deg);
  k_norm<<<GRID_E, TPB, 0, stream>>>(src, dst, ea, deg, norm);

  // ---- layer 1 (F=1) ----
  hipMemsetAsync(pA, 0, (size_t)NN * 4, stream);
  k_prop1<<<GRID_E, TPB, 0, stream>>>(src, dst, norm, x, pA);
  hipMemsetAsync(pB, 0, (size_t)NN * 4, stream);
  k_prop1<<<GRID_E, TPB, 0, stream>>>(src, dst, norm, pA, pB);
  hipMemsetAsync(pC, 0, (size_t)NN * 4, stream);
  k_prop1<<<GRID_E, TPB, 0, stream>>>(src, dst, norm, pB, pC);
  k_combine1<<<GRID_N, TPB, 0, stream>>>(x, pA, pB, pC, W1, b1, h1);

  // ---- layer 2 (F=8) ----
  hipMemsetAsync(pA, 0, (size_t)NN * 32, stream);
  k_prop8<<<GRID_E, TPB, 0, stream>>>(src, dst, norm, h1, pA);
  hipMemsetAsync(pB, 0, (size_t)NN * 32, stream);
  k_prop8<<<GRID_E, TPB, 0, stream>>>(src, dst, norm, pA, pB);
  hipMemsetAsync(pC, 0, (size_t)NN * 32, stream);
  k_prop8<<<GRID_E, TPB, 0, stream>>>(src, dst, norm, pB, pC);
  k_combine8<<<GRID_N, TPB, 0, stream>>>(h1, pA, pB, pC, W2, b2, h2);

  // ---- layer 3 (F=8 -> 1) ----
  hipMemsetAsync(pA, 0, (size_t)NN * 32, stream);
  k_prop8<<<GRID_E, TPB, 0, stream>>>(src, dst, norm, h2, pA);
  hipMemsetAsync(pB, 0, (size_t)NN * 32, stream);
  k_prop8<<<GRID_E, TPB, 0, stream>>>(src, dst, norm, pA, pB);
  hipMemsetAsync(pC, 0, (size_t)NN * 32, stream);
  k_prop8<<<GRID_E, TPB, 0, stream>>>(src, dst, norm, pB, pC);
  k_combine3<<<GRID_N, TPB, 0, stream>>>(h2, pA, pB, pC, W3, b3, h3);

  // ---- layernorm ----
  k_stats<<<GRID_N, TPB, 0, stream>>>(h3, stats);
  k_normkey<<<GRID_N, TPB, 0, stream>>>(h3, stats, hn, key);

  // ---- radix select: k-th largest ----
  hipMemsetAsync(hist, 0, 1024, stream);
  k_hist<24, 0x00000000u><<<GRID_N, TPB, 0, stream>>>(key, prefix, hist);
  k_pick<24><<<1, 1, 0, stream>>>(hist, prefix, target);
  hipMemsetAsync(hist, 0, 1024, stream);
  k_hist<16, 0xFF000000u><<<GRID_N, TPB, 0, stream>>>(key, prefix, hist);
  k_pick<16><<<1, 1, 0, stream>>>(hist, prefix, target);
  hipMemsetAsync(hist, 0, 1024, stream);
  k_hist<8, 0xFFFF0000u><<<GRID_N, TPB, 0, stream>>>(key, prefix, hist);
  k_pick<8><<<1, 1, 0, stream>>>(hist, prefix, target);
  hipMemsetAsync(hist, 0, 1024, stream);
  k_hist<0, 0xFFFFFF00u><<<GRID_N, TPB, 0, stream>>>(key, prefix, hist);
  k_pick<0><<<1, 1, 0, stream>>>(hist, prefix, target);

  // ---- stable membership + output ----
  k_count<<<GRID_N, TPB, 0, stream>>>(key, prefix, partials, cgt);
  k_scan<<<1, 64, 0, stream>>>(partials, offs, kptr, cgt, rr);
  k_final<<<GRID_N, TPB, 0, stream>>>(hn, key, prefix, offs, rr, out);
}

// Round 4
// 924.231 us; speedup vs baseline: 9.3025x; 9.3025x over previous
//
#include <hip/hip_runtime.h>
#include <math.h>

#define NN 100000
#define NE 3200000

static constexpr int TPB = 256;
static constexpr int GRID_E = (NE + TPB - 1) / TPB;       // 12500
static constexpr int GRID_N = (NN + TPB - 1) / TPB;       // 391
static constexpr int GRID_N4 = (NN * 4 + TPB - 1) / TPB;  // 1563 (4 lanes per node)

// ---------------- init small state ----------------
__global__ void k_init(const int* __restrict__ kptr, unsigned* __restrict__ prefix,
                       int* __restrict__ target, int* __restrict__ cgt,
                       double* __restrict__ stats) {
  *prefix = 0u;
  *target = *kptr;
  *cgt = 0;
  stats[0] = 0.0;
  stats[1] = 0.0;
}

// ---------------- edge preprocessing: count + weighted degree ----------------
__global__ void k_cnt_deg(const int* __restrict__ dst, const float* __restrict__ ea,
                          int* __restrict__ cnt, float* __restrict__ deg) {
  int e = blockIdx.x * TPB + threadIdx.x;
  if (e >= NE) return;
  int d = dst[e];
  atomicAdd(&cnt[d], 1);
  atomicAdd(&deg[d], fabsf(ea[e]));
}

__global__ void k_dinv(float* __restrict__ deg) {
  int n = blockIdx.x * TPB + threadIdx.x;
  if (n >= NN) return;
  float dg = deg[n];
  deg[n] = (dg > 0.0f) ? (1.0f / sqrtf(dg)) : 0.0f;
}

// ---------------- exclusive scan of counts -> rowptr (3 kernels) ----------------
__global__ void k_bsum(const int* __restrict__ cnt, int* __restrict__ bsum) {
  __shared__ int sh[TPB];
  int t = threadIdx.x;
  int i = blockIdx.x * TPB + t;
  sh[t] = (i < NN) ? cnt[i] : 0;
  __syncthreads();
  for (int o = TPB / 2; o > 0; o >>= 1) {
    if (t < o) sh[t] += sh[t + o];
    __syncthreads();
  }
  if (t == 0) bsum[blockIdx.x] = sh[0];
}

__global__ void k_bscan(const int* __restrict__ bsum, int* __restrict__ bpre,
                        int* __restrict__ rowptr) {
  if (threadIdx.x == 0) {
    int acc = 0;
    for (int b = 0; b < GRID_N; ++b) { bpre[b] = acc; acc += bsum[b]; }
    rowptr[NN] = NE;
  }
}

__global__ void k_rowptr(const int* __restrict__ cnt, const int* __restrict__ bpre,
                         int* __restrict__ rowptr, int* __restrict__ cursor) {
  __shared__ int sh[TPB];
  int t = threadIdx.x;
  int i = blockIdx.x * TPB + t;
  int v = (i < NN) ? cnt[i] : 0;
  sh[t] = v;
  __syncthreads();
  for (int o = 1; o < TPB; o <<= 1) {
    int a = (t >= o) ? sh[t - o] : 0;
    __syncthreads();
    sh[t] += a;
    __syncthreads();
  }
  if (i < NN) {
    int excl = sh[t] - v + bpre[blockIdx.x];
    rowptr[i] = excl;
    cursor[i] = excl;
  }
}

// ---------------- scatter edges into CSR (src, norm) ----------------
__global__ void k_scatter(const int* __restrict__ src, const int* __restrict__ dst,
                          const float* __restrict__ ea, const float* __restrict__ dinv,
                          int* __restrict__ cursor, int2* __restrict__ ed) {
  int e = blockIdx.x * TPB + threadIdx.x;
  if (e >= NE) return;
  int s = src[e], d = dst[e];
  float w = dinv[s] * fabsf(ea[e]) * dinv[d];
  int pos = atomicAdd(&cursor[d], 1);
  ed[pos] = make_int2(s, __float_as_int(w));
}

// ---------------- gather propagation (no atomics) ----------------
// 4 lanes cooperate per node; shuffle-reduce at the end.
__global__ void g_prop1(const int* __restrict__ rowptr, const int2* __restrict__ ed,
                        const float* __restrict__ hin, float* __restrict__ hout) {
  int t = blockIdx.x * TPB + threadIdx.x;
  int n = t >> 2, r = t & 3;
  if (n >= NN) return;
  int s0 = rowptr[n], s1 = rowptr[n + 1];
  float acc = 0.0f;
  for (int i = s0 + r; i < s1; i += 4) {
    int2 e = ed[i];
    acc += __int_as_float(e.y) * hin[e.x];
  }
  acc += __shfl_xor(acc, 1);
  acc += __shfl_xor(acc, 2);
  if (r == 0) hout[n] = acc;
}

__global__ void g_prop8(const int* __restrict__ rowptr, const int2* __restrict__ ed,
                        const float* __restrict__ hin, float* __restrict__ hout) {
  int t = blockIdx.x * TPB + threadIdx.x;
  int n = t >> 2, r = t & 3;
  if (n >= NN) return;
  int s0 = rowptr[n], s1 = rowptr[n + 1];
  float a0 = 0, a1 = 0, a2 = 0, a3 = 0, a4 = 0, a5 = 0, a6 = 0, a7 = 0;
  for (int i = s0 + r; i < s1; i += 4) {
    int2 e = ed[i];
    float w = __int_as_float(e.y);
    const float4* hp = (const float4*)(hin + (size_t)e.x * 8);
    float4 x = hp[0], y = hp[1];
    a0 += w * x.x; a1 += w * x.y; a2 += w * x.z; a3 += w * x.w;
    a4 += w * y.x; a5 += w * y.y; a6 += w * y.z; a7 += w * y.w;
  }
  #pragma unroll
  for (int m = 1; m <= 2; m <<= 1) {
    a0 += __shfl_xor(a0, m); a1 += __shfl_xor(a1, m);
    a2 += __shfl_xor(a2, m); a3 += __shfl_xor(a3, m);
    a4 += __shfl_xor(a4, m); a5 += __shfl_xor(a5, m);
    a6 += __shfl_xor(a6, m); a7 += __shfl_xor(a7, m);
  }
  if (r == 0) {
    float4* op = (float4*)(hout + (size_t)n * 8);
    op[0] = make_float4(a0, a1, a2, a3);
    op[1] = make_float4(a4, a5, a6, a7);
  }
}

// ---------------- dense combines ----------------
__global__ void k_combine1(const float* __restrict__ x, const float* __restrict__ p1,
                           const float* __restrict__ p2, const float* __restrict__ p3,
                           const float* __restrict__ W, const float* __restrict__ b,
                           float* __restrict__ out) {
  int n = blockIdx.x * TPB + threadIdx.x;
  if (n >= NN) return;
  float h0 = x[n], h1 = p1[n], h2 = p2[n], h3 = p3[n];
  float* op = out + (size_t)n * 8;
  #pragma unroll
  for (int j = 0; j < 8; ++j) {
    float v = b[j] + h0 * W[j] + h1 * W[8 + j] + h2 * W[16 + j] + h3 * W[24 + j];
    op[j] = fmaxf(v, 0.0f);
  }
}

__global__ void k_combine8(const float* __restrict__ p0, const float* __restrict__ p1,
                           const float* __restrict__ p2, const float* __restrict__ p3,
                           const float* __restrict__ W, const float* __restrict__ b,
                           float* __restrict__ out) {
  int n = blockIdx.x * TPB + threadIdx.x;
  if (n >= NN) return;
  float h[4][8];
  const float* ps[4] = {p0, p1, p2, p3};
  #pragma unroll
  for (int i = 0; i < 4; ++i) {
    const float4* hp = (const float4*)(ps[i] + (size_t)n * 8);
    float4 a = hp[0], c = hp[1];
    h[i][0] = a.x; h[i][1] = a.y; h[i][2] = a.z; h[i][3] = a.w;
    h[i][4] = c.x; h[i][5] = c.y; h[i][6] = c.z; h[i][7] = c.w;
  }
  float* op = out + (size_t)n * 8;
  #pragma unroll
  for (int j = 0; j < 8; ++j) {
    float v = b[j];
    #pragma unroll
    for (int i = 0; i < 4; ++i) {
      #pragma unroll
      for (int f = 0; f < 8; ++f) v += h[i][f] * W[i * 64 + f * 8 + j];
    }
    op[j] = fmaxf(v, 0.0f);
  }
}

__global__ void k_combine3(const float* __restrict__ p0, const float* __restrict__ p1,
                           const float* __restrict__ p2, const float* __restrict__ p3,
                           const float* __restrict__ W, const float* __restrict__ b,
                           float* __restrict__ out) {
  int n = blockIdx.x * TPB + threadIdx.x;
  if (n >= NN) return;
  float v = b[0];
  const float* ps[4] = {p0, p1, p2, p3};
  #pragma unroll
  for (int i = 0; i < 4; ++i) {
    const float4* hp = (const float4*)(ps[i] + (size_t)n * 8);
    float4 a = hp[0], c = hp[1];
    v += a.x * W[i * 8 + 0] + a.y * W[i * 8 + 1] + a.z * W[i * 8 + 2] + a.w * W[i * 8 + 3];
    v += c.x * W[i * 8 + 4] + c.y * W[i * 8 + 5] + c.z * W[i * 8 + 6] + c.w * W[i * 8 + 7];
  }
  out[n] = fmaxf(v, 0.0f);
}

// ---------------- layernorm stats ----------------
__global__ void k_stats(const float* __restrict__ h, double* __restrict__ stats) {
  int n = blockIdx.x * TPB + threadIdx.x;
  float v = (n < NN) ? h[n] : 0.0f;
  double s = (double)v, s2 = (double)v * (double)v;
  #pragma unroll
  for (int o = 32; o > 0; o >>= 1) {
    s  += __shfl_down(s, o);
    s2 += __shfl_down(s2, o);
  }
  __shared__ double ls[4], ls2[4];
  int lane = threadIdx.x & 63, w = threadIdx.x >> 6;
  if (lane == 0) { ls[w] = s; ls2[w] = s2; }
  __syncthreads();
  if (threadIdx.x == 0) {
    atomicAdd(&stats[0], ls[0] + ls[1] + ls[2] + ls[3]);
    atomicAdd(&stats[1], ls2[0] + ls2[1] + ls2[2] + ls2[3]);
  }
}

__global__ void k_normkey(const float* __restrict__ h, const double* __restrict__ stats,
                          float* __restrict__ hn, unsigned* __restrict__ key) {
  int n = blockIdx.x * TPB + threadIdx.x;
  if (n >= NN) return;
  double mu = stats[0] / (double)NN;
  double var = stats[1] / (double)NN - mu * mu;
  if (var < 0.0) var = 0.0;
  double invs = 1.0 / sqrt(var + 1e-5);
  float v = (float)(((double)h[n] - mu) * invs);
  hn[n] = v;
  unsigned u = __float_as_uint(v);
  unsigned asc = (u & 0x80000000u) ? ~u : (u | 0x80000000u);
  key[n] = ~asc;
}

// ---------------- radix select (k-th largest) ----------------
template <int SHIFT, unsigned MASK>
__global__ void k_hist(const unsigned* __restrict__ key, const unsigned* __restrict__ prefix,
                       unsigned* __restrict__ hist) {
  __shared__ unsigned lh[256];
  lh[threadIdx.x] = 0;
  __syncthreads();
  int n = blockIdx.x * TPB + threadIdx.x;
  unsigned pfx = *prefix;
  if (n < NN) {
    unsigned kk = key[n];
    if ((kk & MASK) == pfx) atomicAdd(&lh[(kk >> SHIFT) & 0xffu], 1u);
  }
  __syncthreads();
  if (lh[threadIdx.x]) atomicAdd(&hist[threadIdx.x], lh[threadIdx.x]);
}

template <int SHIFT>
__global__ void k_pick(const unsigned* __restrict__ hist, unsigned* __restrict__ prefix,
                       int* __restrict__ target) {
  int t = *target;
  unsigned cum = 0;
  for (int b = 0; b < 256; ++b) {
    unsigned c = hist[b];
    if ((int)(cum + c) >= t) {
      *prefix |= ((unsigned)b) << SHIFT;
      *target = t - (int)cum;
      return;
    }
    cum += c;
  }
}

// ---------------- stable top-k membership ----------------
__global__ void k_count(const unsigned* __restrict__ key, const unsigned* __restrict__ prefix,
                        int* __restrict__ partials, int* __restrict__ cgt) {
  int n = blockIdx.x * TPB + threadIdx.x;
  unsigned T = *prefix;
  bool eq = false, lt = false;
  if (n < NN) {
    unsigned kk = key[n];
    eq = (kk == T);
    lt = (kk < T);
  }
  unsigned long long meq = __ballot(eq);
  unsigned long long mlt = __ballot(lt);
  __shared__ int ce[4], cl[4];
  int lane = threadIdx.x & 63, w = threadIdx.x >> 6;
  if (lane == 0) { ce[w] = __popcll(meq); cl[w] = __popcll(mlt); }
  __syncthreads();
  if (threadIdx.x == 0) {
    partials[blockIdx.x] = ce[0] + ce[1] + ce[2] + ce[3];
    int l = cl[0] + cl[1] + cl[2] + cl[3];
    if (l) atomicAdd(cgt, l);
  }
}

__global__ void k_scan(const int* __restrict__ partials, int* __restrict__ offs,
                       const int* __restrict__ kptr, const int* __restrict__ cgt,
                       int* __restrict__ r) {
  if (threadIdx.x == 0) {
    int acc = 0;
    for (int b = 0; b < GRID_N; ++b) { offs[b] = acc; acc += partials[b]; }
    *r = *kptr - *cgt;
  }
}

__global__ void k_final(const float* __restrict__ hn, const unsigned* __restrict__ key,
                        const unsigned* __restrict__ prefix, const int* __restrict__ offs,
                        const int* __restrict__ rptr, float* __restrict__ out) {
  int n = blockIdx.x * TPB + threadIdx.x;
  unsigned T = *prefix;
  int r = *rptr;
  bool eq = false, lt = false;
  float v = 0.0f;
  if (n < NN) {
    unsigned kk = key[n];
    eq = (kk == T);
    lt = (kk < T);
    v = hn[n];
  }
  unsigned long long m = __ballot(eq);
  __shared__ int wc[4];
  int lane = threadIdx.x & 63, w = threadIdx.x >> 6;
  if (lane == 0) wc[w] = __popcll(m);
  __syncthreads();
  int off = offs[blockIdx.x];
  for (int i = 0; i < w; ++i) off += wc[i];
  off += __popcll(m & ((1ull << lane) - 1ull));
  if (n >= NN) return;
  bool top = lt || (eq && off < r);
  unsigned asc = ~T;
  unsigned orig = (asc & 0x80000000u) ? (asc & 0x7fffffffu) : ~asc;
  float thr = fabsf(__uint_as_float(orig));
  float tkv = top ? 1.0f : -1.0f;
  float z = v - thr + tkv * 0.1f;
  out[2 * n]     = v;
  out[2 * n + 1] = 1.0f / (1.0f + expf(-z));
}

// ---------------- host launch ----------------
extern "C" void kernel_launch(void* const* d_in, const int* in_sizes, int n_in,
                              void* d_out, int out_size, void* d_ws, size_t ws_size,
                              hipStream_t stream) {
  const float* x       = (const float*)d_in[0];
  const float* ea      = (const float*)d_in[1];
  const float* W1      = (const float*)d_in[2];
  const float* b1      = (const float*)d_in[3];
  const float* W2      = (const float*)d_in[4];
  const float* b2      = (const float*)d_in[5];
  const float* W3      = (const float*)d_in[6];
  const float* b3      = (const float*)d_in[7];
  const int* ei        = (const int*)d_in[8];   // int32 on device
  const int* kptr      = (const int*)d_in[9];
  float* out           = (float*)d_out;

  const int* src = ei;        // row 0
  const int* dst = ei + NE;   // row 1

  char* ws = (char*)d_ws;
  size_t off = 0;
  auto alloc = [&](size_t bytes) -> void* {
    void* p = ws + off;
    off += (bytes + 255) & ~(size_t)255;
    return p;
  };

  int2*     ed       = (int2*)alloc((size_t)NE * 8);          // CSR (src, norm)
  int*      cnt      = (int*)alloc((size_t)NN * 4);           // counts, reused as cursor
  int*      rowptr   = (int*)alloc(((size_t)NN + 1) * 4);
  int*      bsum     = (int*)alloc(512 * 4);
  int*      bpre     = (int*)alloc(512 * 4);
  float*    deg      = (float*)alloc((size_t)NN * 4);
  float*    pA       = (float*)alloc((size_t)NN * 8 * 4);
  float*    pB       = (float*)alloc((size_t)NN * 8 * 4);
  float*    pC       = (float*)alloc((size_t)NN * 8 * 4);
  float*    h1       = (float*)alloc((size_t)NN * 8 * 4);
  float*    h2       = (float*)alloc((size_t)NN * 8 * 4);
  float*    h3       = (float*)alloc((size_t)NN * 4);
  float*    hn       = (float*)alloc((size_t)NN * 4);
  unsigned* key      = (unsigned*)alloc((size_t)NN * 4);
  double*   stats    = (double*)alloc(2 * 8);
  unsigned* hist     = (unsigned*)alloc(256 * 4);
  int*      partials = (int*)alloc(512 * 4);
  int*      offs     = (int*)alloc(512 * 4);
  unsigned* prefix   = (unsigned*)alloc(4);
  int*      target   = (int*)alloc(4);
  int*      cgt      = (int*)alloc(4);
  int*      rr       = (int*)alloc(4);

  k_init<<<1, 1, 0, stream>>>(kptr, prefix, target, cgt, stats);

  // ---- build CSR by dst (counting sort), weighted degree ----
  hipMemsetAsync(cnt, 0, (size_t)NN * 4, stream);
  hipMemsetAsync(deg, 0, (size_t)NN * 4, stream);
  k_cnt_deg<<<GRID_E, TPB, 0, stream>>>(dst, ea, cnt, deg);
  k_dinv<<<GRID_N, TPB, 0, stream>>>(deg);
  k_bsum<<<GRID_N, TPB, 0, stream>>>(cnt, bsum);
  k_bscan<<<1, 64, 0, stream>>>(bsum, bpre, rowptr);
  k_rowptr<<<GRID_N, TPB, 0, stream>>>(cnt, bpre, rowptr, cnt);  // cnt becomes cursor
  k_scatter<<<GRID_E, TPB, 0, stream>>>(src, dst, ea, deg, cnt, ed);

  // ---- layer 1 (F=1) ----
  g_prop1<<<GRID_N4, TPB, 0, stream>>>(rowptr, ed, x,  pA);
  g_prop1<<<GRID_N4, TPB, 0, stream>>>(rowptr, ed, pA, pB);
  g_prop1<<<GRID_N4, TPB, 0, stream>>>(rowptr, ed, pB, pC);
  k_combine1<<<GRID_N, TPB, 0, stream>>>(x, pA, pB, pC, W1, b1, h1);

  // ---- layer 2 (F=8) ----
  g_prop8<<<GRID_N4, TPB, 0, stream>>>(rowptr, ed, h1, pA);
  g_prop8<<<GRID_N4, TPB, 0, stream>>>(rowptr, ed, pA, pB);
  g_prop8<<<GRID_N4, TPB, 0, stream>>>(rowptr, ed, pB, pC);
  k_combine8<<<GRID_N, TPB, 0, stream>>>(h1, pA, pB, pC, W2, b2, h2);

  // ---- layer 3 (F=8 -> 1) ----
  g_prop8<<<GRID_N4, TPB, 0, stream>>>(rowptr, ed, h2, pA);
  g_prop8<<<GRID_N4, TPB, 0, stream>>>(rowptr, ed, pA, pB);
  g_prop8<<<GRID_N4, TPB, 0, stream>>>(rowptr, ed, pB, pC);
  k_combine3<<<GRID_N, TPB, 0, stream>>>(h2, pA, pB, pC, W3, b3, h3);

  // ---- layernorm ----
  k_stats<<<GRID_N, TPB, 0, stream>>>(h3, stats);
  k_normkey<<<GRID_N, TPB, 0, stream>>>(h3, stats, hn, key);

  // ---- radix select: k-th largest ----
  hipMemsetAsync(hist, 0, 1024, stream);
  k_hist<24, 0x00000000u><<<GRID_N, TPB, 0, stream>>>(key, prefix, hist);
  k_pick<24><<<1, 1, 0, stream>>>(hist, prefix, target);
  hipMemsetAsync(hist, 0, 1024, stream);
  k_hist<16, 0xFF000000u><<<GRID_N, TPB, 0, stream>>>(key, prefix, hist);
  k_pick<16><<<1, 1, 0, stream>>>(hist, prefix, target);
  hipMemsetAsync(hist, 0, 1024, stream);
  k_hist<8, 0xFFFF0000u><<<GRID_N, TPB, 0, stream>>>(key, prefix, hist);
  k_pick<8><<<1, 1, 0, stream>>>(hist, prefix, target);
  hipMemsetAsync(hist, 0, 1024, stream);
  k_hist<0, 0xFFFFFF00u><<<GRID_N, TPB, 0, stream>>>(key, prefix, hist);
  k_pick<0><<<1, 1, 0, stream>>>(hist, prefix, target);

  // ---- stable membership + output ----
  k_count<<<GRID_N, TPB, 0, stream>>>(key, prefix, partials, cgt);
  k_scan<<<1, 64, 0, stream>>>(partials, offs, kptr, cgt, rr);
  k_final<<<GRID_N, TPB, 0, stream>>>(hn, key, prefix, offs, rr, out);
}

// Round 5
// 710.688 us; speedup vs baseline: 12.0977x; 1.3005x over previous
//
#include <hip/hip_runtime.h>
#include <math.h>

#define NN 100000
#define NE 3200000

static constexpr int TPB = 256;
static constexpr int GRID_E = (NE + TPB - 1) / TPB;       // 12500
static constexpr int GRID_N = (NN + TPB - 1) / TPB;       // 391
static constexpr int GRID_N4 = (NN * 4 + TPB - 1) / TPB;  // 1563 (4 lanes per node)

// ---------------- init small state ----------------
__global__ void k_init(const int* __restrict__ kptr, unsigned* __restrict__ prefix,
                       int* __restrict__ target, int* __restrict__ cgt,
                       double* __restrict__ stats) {
  *prefix = 0u;
  *target = *kptr;
  *cgt = 0;
  stats[0] = 0.0;
  stats[1] = 0.0;
}

// ---------------- pass 1: count only, record per-edge bucket position ----------------
__global__ void k_cnt(const int* __restrict__ dst, int* __restrict__ cnt,
                      int* __restrict__ ppos) {
  int e = blockIdx.x * TPB + threadIdx.x;
  if (e >= NE) return;
  ppos[e] = atomicAdd(&cnt[dst[e]], 1);
}

// ---------------- exclusive scan of counts -> rowptr ----------------
__global__ void k_bsum(const int* __restrict__ cnt, int* __restrict__ bsum) {
  __shared__ int sh[TPB];
  int t = threadIdx.x;
  int i = blockIdx.x * TPB + t;
  sh[t] = (i < NN) ? cnt[i] : 0;
  __syncthreads();
  for (int o = TPB / 2; o > 0; o >>= 1) {
    if (t < o) sh[t] += sh[t + o];
    __syncthreads();
  }
  if (t == 0) bsum[blockIdx.x] = sh[0];
}

__global__ void k_bscan(const int* __restrict__ bsum, int* __restrict__ bpre,
                        int* __restrict__ rowptr) {
  if (threadIdx.x == 0) {
    int acc = 0;
    for (int b = 0; b < GRID_N; ++b) { bpre[b] = acc; acc += bsum[b]; }
    rowptr[NN] = NE;
  }
}

__global__ void k_rowptr(const int* __restrict__ cnt, const int* __restrict__ bpre,
                         int* __restrict__ rowptr) {
  __shared__ int sh[TPB];
  int t = threadIdx.x;
  int i = blockIdx.x * TPB + t;
  int v = (i < NN) ? cnt[i] : 0;
  sh[t] = v;
  __syncthreads();
  for (int o = 1; o < TPB; o <<= 1) {
    int a = (t >= o) ? sh[t - o] : 0;
    __syncthreads();
    sh[t] += a;
    __syncthreads();
  }
  if (i < NN) rowptr[i] = sh[t] - v + bpre[blockIdx.x];
}

// ---------------- pass 2: scatter edges into CSR, NO atomics ----------------
// stores (src, |ea|); norm fix-up happens in the first propagation.
__global__ void k_scatter(const int* __restrict__ src, const int* __restrict__ dst,
                          const float* __restrict__ ea, const int* __restrict__ ppos,
                          const int* __restrict__ rowptr, int2* __restrict__ ed) {
  int e = blockIdx.x * TPB + threadIdx.x;
  if (e >= NE) return;
  int d = dst[e];
  ed[rowptr[d] + ppos[e]] = make_int2(src[e], __float_as_int(fabsf(ea[e])));
}

// ---------------- weighted degree from CSR (coalesced, no atomics) -> dinv ----------------
__global__ void g_degdinv(const int* __restrict__ rowptr, const int2* __restrict__ ed,
                          float* __restrict__ dinv) {
  int t = blockIdx.x * TPB + threadIdx.x;
  int n = t >> 2, r = t & 3;
  if (n >= NN) return;
  int s0 = rowptr[n], s1 = rowptr[n + 1];
  float acc = 0.0f;
  for (int i = s0 + r; i < s1; i += 4) acc += __int_as_float(ed[i].y);
  acc += __shfl_xor(acc, 1);
  acc += __shfl_xor(acc, 2);
  if (r == 0) dinv[n] = (acc > 0.0f) ? (1.0f / sqrtf(acc)) : 0.0f;
}

// ---------------- propagation kernels (gather, no atomics) ----------------
// First F=1 prop fused with norm fix-up: rewrites ed.y = dinv[src]*|ea|*dinv[n].
__global__ void g_prop1fix(const int* __restrict__ rowptr, int2* __restrict__ ed,
                           const float* __restrict__ dinv, const float* __restrict__ hin,
                           float* __restrict__ hout) {
  int t = blockIdx.x * TPB + threadIdx.x;
  int n = t >> 2, r = t & 3;
  if (n >= NN) return;
  int s0 = rowptr[n], s1 = rowptr[n + 1];
  float dn = dinv[n];
  float acc = 0.0f;
  for (int i = s0 + r; i < s1; i += 4) {
    int2 e = ed[i];
    float w = __int_as_float(e.y) * dinv[e.x] * dn;
    ed[i].y = __float_as_int(w);
    acc += w * hin[e.x];
  }
  acc += __shfl_xor(acc, 1);
  acc += __shfl_xor(acc, 2);
  if (r == 0) hout[n] = acc;
}

__global__ void g_prop1(const int* __restrict__ rowptr, const int2* __restrict__ ed,
                        const float* __restrict__ hin, float* __restrict__ hout) {
  int t = blockIdx.x * TPB + threadIdx.x;
  int n = t >> 2, r = t & 3;
  if (n >= NN) return;
  int s0 = rowptr[n], s1 = rowptr[n + 1];
  float acc = 0.0f;
  for (int i = s0 + r; i < s1; i += 4) {
    int2 e = ed[i];
    acc += __int_as_float(e.y) * hin[e.x];
  }
  acc += __shfl_xor(acc, 1);
  acc += __shfl_xor(acc, 2);
  if (r == 0) hout[n] = acc;
}

// Third F=1 prop + fused combine1 (all lanes hold the reduced sum after butterfly).
__global__ void g_prop1c(const int* __restrict__ rowptr, const int2* __restrict__ ed,
                         const float* __restrict__ x, const float* __restrict__ p1,
                         const float* __restrict__ p2, const float* __restrict__ hin,
                         const float* __restrict__ W, const float* __restrict__ b,
                         float* __restrict__ out) {
  int t = blockIdx.x * TPB + threadIdx.x;
  int n = t >> 2, r = t & 3;
  if (n >= NN) return;
  int s0 = rowptr[n], s1 = rowptr[n + 1];
  float acc = 0.0f;
  for (int i = s0 + r; i < s1; i += 4) {
    int2 e = ed[i];
    acc += __int_as_float(e.y) * hin[e.x];
  }
  acc += __shfl_xor(acc, 1);
  acc += __shfl_xor(acc, 2);
  if (r == 0) {
    float h0 = x[n], h1 = p1[n], h2 = p2[n], h3 = acc;
    float* op = out + (size_t)n * 8;
    #pragma unroll
    for (int j = 0; j < 8; ++j) {
      float v = b[j] + h0 * W[j] + h1 * W[8 + j] + h2 * W[16 + j] + h3 * W[24 + j];
      op[j] = fmaxf(v, 0.0f);
    }
  }
}

__global__ void g_prop8(const int* __restrict__ rowptr, const int2* __restrict__ ed,
                        const float* __restrict__ hin, float* __restrict__ hout) {
  int t = blockIdx.x * TPB + threadIdx.x;
  int n = t >> 2, r = t & 3;
  if (n >= NN) return;
  int s0 = rowptr[n], s1 = rowptr[n + 1];
  float a0 = 0, a1 = 0, a2 = 0, a3 = 0, a4 = 0, a5 = 0, a6 = 0, a7 = 0;
  for (int i = s0 + r; i < s1; i += 4) {
    int2 e = ed[i];
    float w = __int_as_float(e.y);
    const float4* hp = (const float4*)(hin + (size_t)e.x * 8);
    float4 xx = hp[0], yy = hp[1];
    a0 += w * xx.x; a1 += w * xx.y; a2 += w * xx.z; a3 += w * xx.w;
    a4 += w * yy.x; a5 += w * yy.y; a6 += w * yy.z; a7 += w * yy.w;
  }
  #pragma unroll
  for (int m = 1; m <= 2; m <<= 1) {
    a0 += __shfl_xor(a0, m); a1 += __shfl_xor(a1, m);
    a2 += __shfl_xor(a2, m); a3 += __shfl_xor(a3, m);
    a4 += __shfl_xor(a4, m); a5 += __shfl_xor(a5, m);
    a6 += __shfl_xor(a6, m); a7 += __shfl_xor(a7, m);
  }
  if (r == 0) {
    float4* op = (float4*)(hout + (size_t)n * 8);
    op[0] = make_float4(a0, a1, a2, a3);
    op[1] = make_float4(a4, a5, a6, a7);
  }
}

// Third F=8 prop + fused combine8 -> h2 (8 outputs).
__global__ void g_prop8c8(const int* __restrict__ rowptr, const int2* __restrict__ ed,
                          const float* __restrict__ p0, const float* __restrict__ p1,
                          const float* __restrict__ hin,
                          const float* __restrict__ W, const float* __restrict__ b,
                          float* __restrict__ out) {
  int t = blockIdx.x * TPB + threadIdx.x;
  int n = t >> 2, r = t & 3;
  if (n >= NN) return;
  int s0 = rowptr[n], s1 = rowptr[n + 1];
  float a0 = 0, a1 = 0, a2 = 0, a3 = 0, a4 = 0, a5 = 0, a6 = 0, a7 = 0;
  for (int i = s0 + r; i < s1; i += 4) {
    int2 e = ed[i];
    float w = __int_as_float(e.y);
    const float4* hp = (const float4*)(hin + (size_t)e.x * 8);
    float4 xx = hp[0], yy = hp[1];
    a0 += w * xx.x; a1 += w * xx.y; a2 += w * xx.z; a3 += w * xx.w;
    a4 += w * yy.x; a5 += w * yy.y; a6 += w * yy.z; a7 += w * yy.w;
  }
  #pragma unroll
  for (int m = 1; m <= 2; m <<= 1) {
    a0 += __shfl_xor(a0, m); a1 += __shfl_xor(a1, m);
    a2 += __shfl_xor(a2, m); a3 += __shfl_xor(a3, m);
    a4 += __shfl_xor(a4, m); a5 += __shfl_xor(a5, m);
    a6 += __shfl_xor(a6, m); a7 += __shfl_xor(a7, m);
  }
  if (r == 0) {
    float h[4][8];
    const float4* hp = (const float4*)(p0 + (size_t)n * 8);
    float4 u = hp[0], v4 = hp[1];
    h[0][0]=u.x; h[0][1]=u.y; h[0][2]=u.z; h[0][3]=u.w; h[0][4]=v4.x; h[0][5]=v4.y; h[0][6]=v4.z; h[0][7]=v4.w;
    hp = (const float4*)(p1 + (size_t)n * 8);
    u = hp[0]; v4 = hp[1];
    h[1][0]=u.x; h[1][1]=u.y; h[1][2]=u.z; h[1][3]=u.w; h[1][4]=v4.x; h[1][5]=v4.y; h[1][6]=v4.z; h[1][7]=v4.w;
    hp = (const float4*)(hin + (size_t)n * 8);   // wait: p2 is the *input* of this prop
    // NOTE: p2 (= S^2 h) is the hin of this kernel evaluated at n
    u = hp[0]; v4 = hp[1];
    h[2][0]=u.x; h[2][1]=u.y; h[2][2]=u.z; h[2][3]=u.w; h[2][4]=v4.x; h[2][5]=v4.y; h[2][6]=v4.z; h[2][7]=v4.w;
    h[3][0]=a0; h[3][1]=a1; h[3][2]=a2; h[3][3]=a3; h[3][4]=a4; h[3][5]=a5; h[3][6]=a6; h[3][7]=a7;
    float* op = out + (size_t)n * 8;
    #pragma unroll
    for (int j = 0; j < 8; ++j) {
      float v = b[j];
      #pragma unroll
      for (int i = 0; i < 4; ++i) {
        #pragma unroll
        for (int f = 0; f < 8; ++f) v += h[i][f] * W[i * 64 + f * 8 + j];
      }
      op[j] = fmaxf(v, 0.0f);
    }
  }
}

// Third F=8 prop of layer 3 + fused combine3 -> scalar h3.
__global__ void g_prop8c3(const int* __restrict__ rowptr, const int2* __restrict__ ed,
                          const float* __restrict__ p0, const float* __restrict__ p1,
                          const float* __restrict__ hin,
                          const float* __restrict__ W, const float* __restrict__ b,
                          float* __restrict__ out) {
  int t = blockIdx.x * TPB + threadIdx.x;
  int n = t >> 2, r = t & 3;
  if (n >= NN) return;
  int s0 = rowptr[n], s1 = rowptr[n + 1];
  float a0 = 0, a1 = 0, a2 = 0, a3 = 0, a4 = 0, a5 = 0, a6 = 0, a7 = 0;
  for (int i = s0 + r; i < s1; i += 4) {
    int2 e = ed[i];
    float w = __int_as_float(e.y);
    const float4* hp = (const float4*)(hin + (size_t)e.x * 8);
    float4 xx = hp[0], yy = hp[1];
    a0 += w * xx.x; a1 += w * xx.y; a2 += w * xx.z; a3 += w * xx.w;
    a4 += w * yy.x; a5 += w * yy.y; a6 += w * yy.z; a7 += w * yy.w;
  }
  #pragma unroll
  for (int m = 1; m <= 2; m <<= 1) {
    a0 += __shfl_xor(a0, m); a1 += __shfl_xor(a1, m);
    a2 += __shfl_xor(a2, m); a3 += __shfl_xor(a3, m);
    a4 += __shfl_xor(a4, m); a5 += __shfl_xor(a5, m);
    a6 += __shfl_xor(a6, m); a7 += __shfl_xor(a7, m);
  }
  if (r == 0) {
    float v = b[0];
    const float4* hp = (const float4*)(p0 + (size_t)n * 8);
    float4 u = hp[0], w4 = hp[1];
    v += u.x*W[0] + u.y*W[1] + u.z*W[2] + u.w*W[3] + w4.x*W[4] + w4.y*W[5] + w4.z*W[6] + w4.w*W[7];
    hp = (const float4*)(p1 + (size_t)n * 8);
    u = hp[0]; w4 = hp[1];
    v += u.x*W[8] + u.y*W[9] + u.z*W[10] + u.w*W[11] + w4.x*W[12] + w4.y*W[13] + w4.z*W[14] + w4.w*W[15];
    hp = (const float4*)(hin + (size_t)n * 8);
    u = hp[0]; w4 = hp[1];
    v += u.x*W[16] + u.y*W[17] + u.z*W[18] + u.w*W[19] + w4.x*W[20] + w4.y*W[21] + w4.z*W[22] + w4.w*W[23];
    v += a0*W[24] + a1*W[25] + a2*W[26] + a3*W[27] + a4*W[28] + a5*W[29] + a6*W[30] + a7*W[31];
    out[n] = fmaxf(v, 0.0f);
  }
}

// ---------------- F=1 -> 8 combine happens in g_prop1c; F=8 first prop needs h1 ----------------

// ---------------- layernorm stats ----------------
__global__ void k_stats(const float* __restrict__ h, double* __restrict__ stats) {
  int n = blockIdx.x * TPB + threadIdx.x;
  float v = (n < NN) ? h[n] : 0.0f;
  double s = (double)v, s2 = (double)v * (double)v;
  #pragma unroll
  for (int o = 32; o > 0; o >>= 1) {
    s  += __shfl_down(s, o);
    s2 += __shfl_down(s2, o);
  }
  __shared__ double ls[4], ls2[4];
  int lane = threadIdx.x & 63, w = threadIdx.x >> 6;
  if (lane == 0) { ls[w] = s; ls2[w] = s2; }
  __syncthreads();
  if (threadIdx.x == 0) {
    atomicAdd(&stats[0], ls[0] + ls[1] + ls[2] + ls[3]);
    atomicAdd(&stats[1], ls2[0] + ls2[1] + ls2[2] + ls2[3]);
  }
}

__global__ void k_normkey(const float* __restrict__ h, const double* __restrict__ stats,
                          float* __restrict__ hn, unsigned* __restrict__ key) {
  int n = blockIdx.x * TPB + threadIdx.x;
  if (n >= NN) return;
  double mu = stats[0] / (double)NN;
  double var = stats[1] / (double)NN - mu * mu;
  if (var < 0.0) var = 0.0;
  double invs = 1.0 / sqrt(var + 1e-5);
  float v = (float)(((double)h[n] - mu) * invs);
  hn[n] = v;
  unsigned u = __float_as_uint(v);
  unsigned asc = (u & 0x80000000u) ? ~u : (u | 0x80000000u);
  key[n] = ~asc;
}

// ---------------- radix select (k-th largest) ----------------
template <int SHIFT, unsigned MASK>
__global__ void k_hist(const unsigned* __restrict__ key, const unsigned* __restrict__ prefix,
                       unsigned* __restrict__ hist) {
  __shared__ unsigned lh[256];
  lh[threadIdx.x] = 0;
  __syncthreads();
  int n = blockIdx.x * TPB + threadIdx.x;
  unsigned pfx = *prefix;
  if (n < NN) {
    unsigned kk = key[n];
    if ((kk & MASK) == pfx) atomicAdd(&lh[(kk >> SHIFT) & 0xffu], 1u);
  }
  __syncthreads();
  if (lh[threadIdx.x]) atomicAdd(&hist[threadIdx.x], lh[threadIdx.x]);
}

template <int SHIFT>
__global__ void k_pick(const unsigned* __restrict__ hist, unsigned* __restrict__ prefix,
                       int* __restrict__ target) {
  int t = *target;
  unsigned cum = 0;
  for (int b = 0; b < 256; ++b) {
    unsigned c = hist[b];
    if ((int)(cum + c) >= t) {
      *prefix |= ((unsigned)b) << SHIFT;
      *target = t - (int)cum;
      return;
    }
    cum += c;
  }
}

// ---------------- stable top-k membership ----------------
__global__ void k_count(const unsigned* __restrict__ key, const unsigned* __restrict__ prefix,
                        int* __restrict__ partials, int* __restrict__ cgt) {
  int n = blockIdx.x * TPB + threadIdx.x;
  unsigned T = *prefix;
  bool eq = false, lt = false;
  if (n < NN) {
    unsigned kk = key[n];
    eq = (kk == T);
    lt = (kk < T);
  }
  unsigned long long meq = __ballot(eq);
  unsigned long long mlt = __ballot(lt);
  __shared__ int ce[4], cl[4];
  int lane = threadIdx.x & 63, w = threadIdx.x >> 6;
  if (lane == 0) { ce[w] = __popcll(meq); cl[w] = __popcll(mlt); }
  __syncthreads();
  if (threadIdx.x == 0) {
    partials[blockIdx.x] = ce[0] + ce[1] + ce[2] + ce[3];
    int l = cl[0] + cl[1] + cl[2] + cl[3];
    if (l) atomicAdd(cgt, l);
  }
}

__global__ void k_scan(const int* __restrict__ partials, int* __restrict__ offs,
                       const int* __restrict__ kptr, const int* __restrict__ cgt,
                       int* __restrict__ r) {
  if (threadIdx.x == 0) {
    int acc = 0;
    for (int b = 0; b < GRID_N; ++b) { offs[b] = acc; acc += partials[b]; }
    *r = *kptr - *cgt;
  }
}

__global__ void k_final(const float* __restrict__ hn, const unsigned* __restrict__ key,
                        const unsigned* __restrict__ prefix, const int* __restrict__ offs,
                        const int* __restrict__ rptr, float* __restrict__ out) {
  int n = blockIdx.x * TPB + threadIdx.x;
  unsigned T = *prefix;
  int r = *rptr;
  bool eq = false, lt = false;
  float v = 0.0f;
  if (n < NN) {
    unsigned kk = key[n];
    eq = (kk == T);
    lt = (kk < T);
    v = hn[n];
  }
  unsigned long long m = __ballot(eq);
  __shared__ int wc[4];
  int lane = threadIdx.x & 63, w = threadIdx.x >> 6;
  if (lane == 0) wc[w] = __popcll(m);
  __syncthreads();
  int off = offs[blockIdx.x];
  for (int i = 0; i < w; ++i) off += wc[i];
  off += __popcll(m & ((1ull << lane) - 1ull));
  if (n >= NN) return;
  bool top = lt || (eq && off < r);
  unsigned asc = ~T;
  unsigned orig = (asc & 0x80000000u) ? (asc & 0x7fffffffu) : ~asc;
  float thr = fabsf(__uint_as_float(orig));
  float tkv = top ? 1.0f : -1.0f;
  float z = v - thr + tkv * 0.1f;
  out[2 * n]     = v;
  out[2 * n + 1] = 1.0f / (1.0f + expf(-z));
}

// ---------------- host launch ----------------
extern "C" void kernel_launch(void* const* d_in, const int* in_sizes, int n_in,
                              void* d_out, int out_size, void* d_ws, size_t ws_size,
                              hipStream_t stream) {
  const float* x       = (const float*)d_in[0];
  const float* ea      = (const float*)d_in[1];
  const float* W1      = (const float*)d_in[2];
  const float* b1      = (const float*)d_in[3];
  const float* W2      = (const float*)d_in[4];
  const float* b2      = (const float*)d_in[5];
  const float* W3      = (const float*)d_in[6];
  const float* b3      = (const float*)d_in[7];
  const int* ei        = (const int*)d_in[8];   // int32 on device
  const int* kptr      = (const int*)d_in[9];
  float* out           = (float*)d_out;

  const int* src = ei;        // row 0
  const int* dst = ei + NE;   // row 1

  char* ws = (char*)d_ws;
  size_t off = 0;
  auto alloc = [&](size_t bytes) -> void* {
    void* p = ws + off;
    off += (bytes + 255) & ~(size_t)255;
    return p;
  };

  int2*     ed       = (int2*)alloc((size_t)NE * 8);    // CSR (src, w)
  int*      ppos     = (int*)alloc((size_t)NE * 4);     // per-edge bucket position
  int*      cnt      = (int*)alloc((size_t)NN * 4);
  int*      rowptr   = (int*)alloc(((size_t)NN + 1) * 4);
  int*      bsum     = (int*)alloc(512 * 4);
  int*      bpre     = (int*)alloc(512 * 4);
  float*    dinv     = (float*)alloc((size_t)NN * 4);
  float*    pA       = (float*)alloc((size_t)NN * 8 * 4);
  float*    pB       = (float*)alloc((size_t)NN * 8 * 4);
  float*    h1       = (float*)alloc((size_t)NN * 8 * 4);
  float*    h2       = (float*)alloc((size_t)NN * 8 * 4);
  float*    h3       = (float*)alloc((size_t)NN * 4);
  float*    hn       = (float*)alloc((size_t)NN * 4);
  unsigned* key      = (unsigned*)alloc((size_t)NN * 4);
  double*   stats    = (double*)alloc(2 * 8);
  unsigned* hist     = (unsigned*)alloc(256 * 4);
  int*      partials = (int*)alloc(512 * 4);
  int*      offs     = (int*)alloc(512 * 4);
  unsigned* prefix   = (unsigned*)alloc(4);
  int*      target   = (int*)alloc(4);
  int*      cgt      = (int*)alloc(4);
  int*      rr       = (int*)alloc(4);

  k_init<<<1, 1, 0, stream>>>(kptr, prefix, target, cgt, stats);

  // ---- build CSR by dst: count (+ppos), scan, scatter (no cursor atomics) ----
  hipMemsetAsync(cnt, 0, (size_t)NN * 4, stream);
  k_cnt<<<GRID_E, TPB, 0, stream>>>(dst, cnt, ppos);
  k_bsum<<<GRID_N, TPB, 0, stream>>>(cnt, bsum);
  k_bscan<<<1, 64, 0, stream>>>(bsum, bpre, rowptr);
  k_rowptr<<<GRID_N, TPB, 0, stream>>>(cnt, bpre, rowptr);
  k_scatter<<<GRID_E, TPB, 0, stream>>>(src, dst, ea, ppos, rowptr, ed);

  // ---- weighted degree + dinv from CSR (no atomics) ----
  g_degdinv<<<GRID_N4, TPB, 0, stream>>>(rowptr, ed, dinv);

  // ---- layer 1 (F=1): prop1+normfix, prop1, prop1+combine1 ----
  g_prop1fix<<<GRID_N4, TPB, 0, stream>>>(rowptr, ed, dinv, x, pA);
  g_prop1<<<GRID_N4, TPB, 0, stream>>>(rowptr, ed, pA, pB);
  g_prop1c<<<GRID_N4, TPB, 0, stream>>>(rowptr, ed, x, pA, pB, pB, W1, b1, h1);

  // ---- layer 2 (F=8) ----
  g_prop8<<<GRID_N4, TPB, 0, stream>>>(rowptr, ed, h1, pA);
  g_prop8<<<GRID_N4, TPB, 0, stream>>>(rowptr, ed, pA, pB);
  g_prop8c8<<<GRID_N4, TPB, 0, stream>>>(rowptr, ed, h1, pA, pB, W2, b2, h2);

  // ---- layer 3 (F=8 -> 1) ----
  g_prop8<<<GRID_N4, TPB, 0, stream>>>(rowptr, ed, h2, pA);
  g_prop8<<<GRID_N4, TPB, 0, stream>>>(rowptr, ed, pA, pB);
  g_prop8c3<<<GRID_N4, TPB, 0, stream>>>(rowptr, ed, h2, pA, pB, W3, b3, h3);

  // ---- layernorm ----
  k_stats<<<GRID_N, TPB, 0, stream>>>(h3, stats);
  k_normkey<<<GRID_N, TPB, 0, stream>>>(h3, stats, hn, key);

  // ---- radix select: k-th largest ----
  hipMemsetAsync(hist, 0, 1024, stream);
  k_hist<24, 0x00000000u><<<GRID_N, TPB, 0, stream>>>(key, prefix, hist);
  k_pick<24><<<1, 1, 0, stream>>>(hist, prefix, target);
  hipMemsetAsync(hist, 0, 1024, stream);
  k_hist<16, 0xFF000000u><<<GRID_N, TPB, 0, stream>>>(key, prefix, hist);
  k_pick<16><<<1, 1, 0, stream>>>(hist, prefix, target);
  hipMemsetAsync(hist, 0, 1024, stream);
  k_hist<8, 0xFFFF0000u><<<GRID_N, TPB, 0, stream>>>(key, prefix, hist);
  k_pick<8><<<1, 1, 0, stream>>>(hist, prefix, target);
  hipMemsetAsync(hist, 0, 1024, stream);
  k_hist<0, 0xFFFFFF00u><<<GRID_N, TPB, 0, stream>>>(key, prefix, hist);
  k_pick<0><<<1, 1, 0, stream>>>(hist, prefix, target);

  // ---- stable membership + output ----
  k_count<<<GRID_N, TPB, 0, stream>>>(key, prefix, partials, cgt);
  k_scan<<<1, 64, 0, stream>>>(partials, offs, kptr, cgt, rr);
  k_final<<<GRID_N, TPB, 0, stream>>>(hn, key, prefix, offs, rr, out);
}

// Round 6
// 670.099 us; speedup vs baseline: 12.8305x; 1.0606x over previous
//
#include <hip/hip_runtime.h>
#include <math.h>

#define NN 100000
#define NE 3200000
#define NSUB 4

static constexpr int TPB = 256;
static constexpr int GRID_E = (NE + TPB - 1) / TPB;       // 12500
static constexpr int GRID_N = (NN + TPB - 1) / TPB;       // 391
static constexpr int GRID_N4 = (NN * 4 + TPB - 1) / TPB;  // 1563 (4 lanes per node)

// ---------------- init small state ----------------
__global__ void k_init(const int* __restrict__ kptr, unsigned* __restrict__ prefix,
                       int* __restrict__ target, double* __restrict__ stats) {
  *prefix = 0u;
  *target = *kptr;
  stats[0] = 0.0;
  stats[1] = 0.0;
}

// ---------------- pass 1: 4-way sub-histogram count, record per-edge position ----------------
__global__ void k_cnt(const int* __restrict__ dst, int* __restrict__ cnt,
                      int* __restrict__ ppos) {
  int e = blockIdx.x * TPB + threadIdx.x;
  if (e >= NE) return;
  int sub = blockIdx.x & (NSUB - 1);
  ppos[e] = atomicAdd(&cnt[sub * NN + dst[e]], 1);
}

// ---------------- per-node totals + in-row sub-offsets (in place) ----------------
__global__ void k_tot(int* __restrict__ cnt, int* __restrict__ tot) {
  int n = blockIdx.x * TPB + threadIdx.x;
  if (n >= NN) return;
  int c0 = cnt[n], c1 = cnt[NN + n], c2 = cnt[2 * NN + n], c3 = cnt[3 * NN + n];
  cnt[n] = 0;
  cnt[NN + n] = c0;
  cnt[2 * NN + n] = c0 + c1;
  cnt[3 * NN + n] = c0 + c1 + c2;
  tot[n] = c0 + c1 + c2 + c3;
}

// ---------------- exclusive scan of totals -> rowptr ----------------
__global__ void k_bsum(const int* __restrict__ tot, int* __restrict__ bsum) {
  __shared__ int sh[TPB];
  int t = threadIdx.x;
  int i = blockIdx.x * TPB + t;
  sh[t] = (i < NN) ? tot[i] : 0;
  __syncthreads();
  for (int o = TPB / 2; o > 0; o >>= 1) {
    if (t < o) sh[t] += sh[t + o];
    __syncthreads();
  }
  if (t == 0) bsum[blockIdx.x] = sh[0];
}

__global__ void k_bscan(const int* __restrict__ bsum, int* __restrict__ bpre,
                        int* __restrict__ rowptr) {
  if (threadIdx.x == 0) {
    int acc = 0;
    for (int b = 0; b < GRID_N; ++b) { bpre[b] = acc; acc += bsum[b]; }
    rowptr[NN] = NE;
  }
}

__global__ void k_rowptr(const int* __restrict__ tot, const int* __restrict__ bpre,
                         int* __restrict__ rowptr) {
  __shared__ int sh[TPB];
  int t = threadIdx.x;
  int i = blockIdx.x * TPB + t;
  int v = (i < NN) ? tot[i] : 0;
  sh[t] = v;
  __syncthreads();
  for (int o = 1; o < TPB; o <<= 1) {
    int a = (t >= o) ? sh[t - o] : 0;
    __syncthreads();
    sh[t] += a;
    __syncthreads();
  }
  if (i < NN) rowptr[i] = sh[t] - v + bpre[blockIdx.x];
}

// ---------------- pass 2: scatter edges into CSR, NO atomics ----------------
__global__ void k_scatter(const int* __restrict__ src, const int* __restrict__ dst,
                          const float* __restrict__ ea, const int* __restrict__ ppos,
                          const int* __restrict__ rowptr, const int* __restrict__ cnt,
                          int2* __restrict__ ed) {
  int e = blockIdx.x * TPB + threadIdx.x;
  if (e >= NE) return;
  int sub = blockIdx.x & (NSUB - 1);
  int d = dst[e];
  int pos = rowptr[d] + cnt[sub * NN + d] + ppos[e];
  ed[pos] = make_int2(src[e], __float_as_int(fabsf(ea[e])));
}

// ---------------- weighted degree from CSR -> dinv ----------------
__global__ void g_degdinv(const int* __restrict__ rowptr, const int2* __restrict__ ed,
                          float* __restrict__ dinv) {
  int t = blockIdx.x * TPB + threadIdx.x;
  int n = t >> 2, r = t & 3;
  if (n >= NN) return;
  int s0 = rowptr[n], s1 = rowptr[n + 1];
  float acc = 0.0f;
  for (int i = s0 + r; i < s1; i += 4) acc += __int_as_float(ed[i].y);
  acc += __shfl_xor(acc, 1);
  acc += __shfl_xor(acc, 2);
  if (r == 0) dinv[n] = (acc > 0.0f) ? (1.0f / sqrtf(acc)) : 0.0f;
}

// ---------------- scalar propagation kernels ----------------
// First prop fused with norm fix-up: rewrites ed.y = dinv[src]*|ea|*dinv[n].
__global__ void g_prop1fix(const int* __restrict__ rowptr, int2* __restrict__ ed,
                           const float* __restrict__ dinv, const float* __restrict__ hin,
                           float* __restrict__ hout) {
  int t = blockIdx.x * TPB + threadIdx.x;
  int n = t >> 2, r = t & 3;
  if (n >= NN) return;
  int s0 = rowptr[n], s1 = rowptr[n + 1];
  float dn = dinv[n];
  float acc = 0.0f;
  for (int i = s0 + r; i < s1; i += 4) {
    int2 e = ed[i];
    float w = __int_as_float(e.y) * dinv[e.x] * dn;
    ed[i].y = __float_as_int(w);
    acc += w * hin[e.x];
  }
  acc += __shfl_xor(acc, 1);
  acc += __shfl_xor(acc, 2);
  if (r == 0) hout[n] = acc;
}

__global__ void g_prop1(const int* __restrict__ rowptr, const int2* __restrict__ ed,
                        const float* __restrict__ hin, float* __restrict__ hout) {
  int t = blockIdx.x * TPB + threadIdx.x;
  int n = t >> 2, r = t & 3;
  if (n >= NN) return;
  int s0 = rowptr[n], s1 = rowptr[n + 1];
  float acc = 0.0f;
  for (int i = s0 + r; i < s1; i += 4) {
    int2 e = ed[i];
    acc += __int_as_float(e.y) * hin[e.x];
  }
  acc += __shfl_xor(acc, 1);
  acc += __shfl_xor(acc, 2);
  if (r == 0) hout[n] = acc;
}

// out[n] = (addv[n] + S(gsrc)[n]), optional relu. Used for layer-3 Horner chain.
template <int RELU>
__global__ void g_prop1add(const int* __restrict__ rowptr, const int2* __restrict__ ed,
                           const float* __restrict__ gsrc, const float* __restrict__ addv,
                           float* __restrict__ out) {
  int t = blockIdx.x * TPB + threadIdx.x;
  int n = t >> 2, r = t & 3;
  if (n >= NN) return;
  int s0 = rowptr[n], s1 = rowptr[n + 1];
  float acc = 0.0f;
  for (int i = s0 + r; i < s1; i += 4) {
    int2 e = ed[i];
    acc += __int_as_float(e.y) * gsrc[e.x];
  }
  acc += __shfl_xor(acc, 1);
  acc += __shfl_xor(acc, 2);
  if (r == 0) {
    float v = addv[n] + acc;
    out[n] = RELU ? fmaxf(v, 0.0f) : v;
  }
}

// Third F=1 prop + fused combine1 -> h1 (8-wide).
__global__ void g_prop1c(const int* __restrict__ rowptr, const int2* __restrict__ ed,
                         const float* __restrict__ x, const float* __restrict__ p1,
                         const float* __restrict__ p2, const float* __restrict__ hin,
                         const float* __restrict__ W, const float* __restrict__ b,
                         float* __restrict__ out) {
  int t = blockIdx.x * TPB + threadIdx.x;
  int n = t >> 2, r = t & 3;
  if (n >= NN) return;
  int s0 = rowptr[n], s1 = rowptr[n + 1];
  float acc = 0.0f;
  for (int i = s0 + r; i < s1; i += 4) {
    int2 e = ed[i];
    acc += __int_as_float(e.y) * hin[e.x];
  }
  acc += __shfl_xor(acc, 1);
  acc += __shfl_xor(acc, 2);
  if (r == 0) {
    float h0 = x[n], h1 = p1[n], h2 = p2[n], h3 = acc;
    float* op = out + (size_t)n * 8;
    #pragma unroll
    for (int j = 0; j < 8; ++j) {
      float v = b[j] + h0 * W[j] + h1 * W[8 + j] + h2 * W[16 + j] + h3 * W[24 + j];
      op[j] = fmaxf(v, 0.0f);
    }
  }
}

// ---------------- 8-wide propagation ----------------
__global__ void g_prop8(const int* __restrict__ rowptr, const int2* __restrict__ ed,
                        const float* __restrict__ hin, float* __restrict__ hout) {
  int t = blockIdx.x * TPB + threadIdx.x;
  int n = t >> 2, r = t & 3;
  if (n >= NN) return;
  int s0 = rowptr[n], s1 = rowptr[n + 1];
  float a0 = 0, a1 = 0, a2 = 0, a3 = 0, a4 = 0, a5 = 0, a6 = 0, a7 = 0;
  for (int i = s0 + r; i < s1; i += 4) {
    int2 e = ed[i];
    float w = __int_as_float(e.y);
    const float4* hp = (const float4*)(hin + (size_t)e.x * 8);
    float4 xx = hp[0], yy = hp[1];
    a0 += w * xx.x; a1 += w * xx.y; a2 += w * xx.z; a3 += w * xx.w;
    a4 += w * yy.x; a5 += w * yy.y; a6 += w * yy.z; a7 += w * yy.w;
  }
  #pragma unroll
  for (int m = 1; m <= 2; m <<= 1) {
    a0 += __shfl_xor(a0, m); a1 += __shfl_xor(a1, m);
    a2 += __shfl_xor(a2, m); a3 += __shfl_xor(a3, m);
    a4 += __shfl_xor(a4, m); a5 += __shfl_xor(a5, m);
    a6 += __shfl_xor(a6, m); a7 += __shfl_xor(a7, m);
  }
  if (r == 0) {
    float4* op = (float4*)(hout + (size_t)n * 8);
    op[0] = make_float4(a0, a1, a2, a3);
    op[1] = make_float4(a4, a5, a6, a7);
  }
}

// Layer-2 final prop + fused combine8 (h2 in regs) + layer-3 scalar projections.
// Writes g0 = h2.W3_0 + b3, s1..s3 = h2.W3_i  (h2 never materialized).
__global__ void g_prop8l3(const int* __restrict__ rowptr, const int2* __restrict__ ed,
                          const float* __restrict__ p0, const float* __restrict__ p1,
                          const float* __restrict__ hin,
                          const float* __restrict__ W2, const float* __restrict__ b2,
                          const float* __restrict__ W3, const float* __restrict__ b3,
                          float* __restrict__ g0o, float* __restrict__ s1o,
                          float* __restrict__ s2o, float* __restrict__ s3o) {
  int t = blockIdx.x * TPB + threadIdx.x;
  int n = t >> 2, r = t & 3;
  if (n >= NN) return;
  int s0 = rowptr[n], s1 = rowptr[n + 1];
  float a0 = 0, a1 = 0, a2 = 0, a3 = 0, a4 = 0, a5 = 0, a6 = 0, a7 = 0;
  for (int i = s0 + r; i < s1; i += 4) {
    int2 e = ed[i];
    float w = __int_as_float(e.y);
    const float4* hp = (const float4*)(hin + (size_t)e.x * 8);
    float4 xx = hp[0], yy = hp[1];
    a0 += w * xx.x; a1 += w * xx.y; a2 += w * xx.z; a3 += w * xx.w;
    a4 += w * yy.x; a5 += w * yy.y; a6 += w * yy.z; a7 += w * yy.w;
  }
  #pragma unroll
  for (int m = 1; m <= 2; m <<= 1) {
    a0 += __shfl_xor(a0, m); a1 += __shfl_xor(a1, m);
    a2 += __shfl_xor(a2, m); a3 += __shfl_xor(a3, m);
    a4 += __shfl_xor(a4, m); a5 += __shfl_xor(a5, m);
    a6 += __shfl_xor(a6, m); a7 += __shfl_xor(a7, m);
  }
  if (r == 0) {
    float h[4][8];
    const float4* hp = (const float4*)(p0 + (size_t)n * 8);
    float4 u = hp[0], v4 = hp[1];
    h[0][0]=u.x; h[0][1]=u.y; h[0][2]=u.z; h[0][3]=u.w; h[0][4]=v4.x; h[0][5]=v4.y; h[0][6]=v4.z; h[0][7]=v4.w;
    hp = (const float4*)(p1 + (size_t)n * 8);
    u = hp[0]; v4 = hp[1];
    h[1][0]=u.x; h[1][1]=u.y; h[1][2]=u.z; h[1][3]=u.w; h[1][4]=v4.x; h[1][5]=v4.y; h[1][6]=v4.z; h[1][7]=v4.w;
    hp = (const float4*)(hin + (size_t)n * 8);
    u = hp[0]; v4 = hp[1];
    h[2][0]=u.x; h[2][1]=u.y; h[2][2]=u.z; h[2][3]=u.w; h[2][4]=v4.x; h[2][5]=v4.y; h[2][6]=v4.z; h[2][7]=v4.w;
    h[3][0]=a0; h[3][1]=a1; h[3][2]=a2; h[3][3]=a3; h[3][4]=a4; h[3][5]=a5; h[3][6]=a6; h[3][7]=a7;
    float hv[8];
    #pragma unroll
    for (int j = 0; j < 8; ++j) {
      float v = b2[j];
      #pragma unroll
      for (int i = 0; i < 4; ++i) {
        #pragma unroll
        for (int f = 0; f < 8; ++f) v += h[i][f] * W2[i * 64 + f * 8 + j];
      }
      hv[j] = fmaxf(v, 0.0f);
    }
    float g0 = b3[0], sv1 = 0, sv2 = 0, sv3 = 0;
    #pragma unroll
    for (int f = 0; f < 8; ++f) {
      g0  += hv[f] * W3[f];
      sv1 += hv[f] * W3[8 + f];
      sv2 += hv[f] * W3[16 + f];
      sv3 += hv[f] * W3[24 + f];
    }
    g0o[n] = g0; s1o[n] = sv1; s2o[n] = sv2; s3o[n] = sv3;
  }
}

// ---------------- layernorm stats ----------------
__global__ void k_stats(const float* __restrict__ h, double* __restrict__ stats) {
  int n = blockIdx.x * TPB + threadIdx.x;
  float v = (n < NN) ? h[n] : 0.0f;
  double s = (double)v, s2 = (double)v * (double)v;
  #pragma unroll
  for (int o = 32; o > 0; o >>= 1) {
    s  += __shfl_down(s, o);
    s2 += __shfl_down(s2, o);
  }
  __shared__ double ls[4], ls2[4];
  int lane = threadIdx.x & 63, w = threadIdx.x >> 6;
  if (lane == 0) { ls[w] = s; ls2[w] = s2; }
  __syncthreads();
  if (threadIdx.x == 0) {
    atomicAdd(&stats[0], ls[0] + ls[1] + ls[2] + ls[3]);
    atomicAdd(&stats[1], ls2[0] + ls2[1] + ls2[2] + ls2[3]);
  }
}

__global__ void k_normkey(const float* __restrict__ h, const double* __restrict__ stats,
                          float* __restrict__ hn, unsigned* __restrict__ key) {
  int n = blockIdx.x * TPB + threadIdx.x;
  if (n >= NN) return;
  double mu = stats[0] / (double)NN;
  double var = stats[1] / (double)NN - mu * mu;
  if (var < 0.0) var = 0.0;
  double invs = 1.0 / sqrt(var + 1e-5);
  float v = (float)(((double)h[n] - mu) * invs);
  hn[n] = v;
  unsigned u = __float_as_uint(v);
  unsigned asc = (u & 0x80000000u) ? ~u : (u | 0x80000000u);
  key[n] = ~asc;
}

// ---------------- radix select (k-th largest) ----------------
template <int SHIFT, unsigned MASK>
__global__ void k_hist(const unsigned* __restrict__ key, const unsigned* __restrict__ prefix,
                       unsigned* __restrict__ hist) {
  __shared__ unsigned lh[256];
  lh[threadIdx.x] = 0;
  __syncthreads();
  int n = blockIdx.x * TPB + threadIdx.x;
  unsigned pfx = *prefix;
  if (n < NN) {
    unsigned kk = key[n];
    if ((kk & MASK) == pfx) atomicAdd(&lh[(kk >> SHIFT) & 0xffu], 1u);
  }
  __syncthreads();
  if (lh[threadIdx.x]) atomicAdd(&hist[threadIdx.x], lh[threadIdx.x]);
}

template <int SHIFT>
__global__ void k_pick(const unsigned* __restrict__ hist, unsigned* __restrict__ prefix,
                       int* __restrict__ target) {
  int t = *target;
  unsigned cum = 0;
  for (int b = 0; b < 256; ++b) {
    unsigned c = hist[b];
    if ((int)(cum + c) >= t) {
      *prefix |= ((unsigned)b) << SHIFT;
      *target = t - (int)cum;   // after last pass: rank within the tied keys
      return;
    }
    cum += c;
  }
}

// ---------------- stable top-k membership ----------------
__global__ void k_count(const unsigned* __restrict__ key, const unsigned* __restrict__ prefix,
                        int* __restrict__ partials) {
  int n = blockIdx.x * TPB + threadIdx.x;
  unsigned T = *prefix;
  bool eq = (n < NN) && (key[n] == T);
  unsigned long long meq = __ballot(eq);
  __shared__ int ce[4];
  int lane = threadIdx.x & 63, w = threadIdx.x >> 6;
  if (lane == 0) ce[w] = __popcll(meq);
  __syncthreads();
  if (threadIdx.x == 0) partials[blockIdx.x] = ce[0] + ce[1] + ce[2] + ce[3];
}

__global__ void k_scan(const int* __restrict__ partials, int* __restrict__ offs) {
  if (threadIdx.x == 0) {
    int acc = 0;
    for (int b = 0; b < GRID_N; ++b) { offs[b] = acc; acc += partials[b]; }
  }
}

__global__ void k_final(const float* __restrict__ hn, const unsigned* __restrict__ key,
                        const unsigned* __restrict__ prefix, const int* __restrict__ offs,
                        const int* __restrict__ rptr, float* __restrict__ out) {
  int n = blockIdx.x * TPB + threadIdx.x;
  unsigned T = *prefix;
  int r = *rptr;   // number of tied keys (ascending index) inside top-k
  bool eq = false, lt = false;
  float v = 0.0f;
  if (n < NN) {
    unsigned kk = key[n];
    eq = (kk == T);
    lt = (kk < T);
    v = hn[n];
  }
  unsigned long long m = __ballot(eq);
  __shared__ int wc[4];
  int lane = threadIdx.x & 63, w = threadIdx.x >> 6;
  if (lane == 0) wc[w] = __popcll(m);
  __syncthreads();
  int off = offs[blockIdx.x];
  for (int i = 0; i < w; ++i) off += wc[i];
  off += __popcll(m & ((1ull << lane) - 1ull));
  if (n >= NN) return;
  bool top = lt || (eq && off < r);
  unsigned asc = ~T;
  unsigned orig = (asc & 0x80000000u) ? (asc & 0x7fffffffu) : ~asc;
  float thr = fabsf(__uint_as_float(orig));
  float tkv = top ? 1.0f : -1.0f;
  float z = v - thr + tkv * 0.1f;
  out[2 * n]     = v;
  out[2 * n + 1] = 1.0f / (1.0f + expf(-z));
}

// ---------------- host launch ----------------
extern "C" void kernel_launch(void* const* d_in, const int* in_sizes, int n_in,
                              void* d_out, int out_size, void* d_ws, size_t ws_size,
                              hipStream_t stream) {
  const float* x       = (const float*)d_in[0];
  const float* ea      = (const float*)d_in[1];
  const float* W1      = (const float*)d_in[2];
  const float* b1      = (const float*)d_in[3];
  const float* W2      = (const float*)d_in[4];
  const float* b2      = (const float*)d_in[5];
  const float* W3      = (const float*)d_in[6];
  const float* b3      = (const float*)d_in[7];
  const int* ei        = (const int*)d_in[8];   // int32 on device
  const int* kptr      = (const int*)d_in[9];
  float* out           = (float*)d_out;

  const int* src = ei;        // row 0
  const int* dst = ei + NE;   // row 1

  char* ws = (char*)d_ws;
  size_t off = 0;
  auto alloc = [&](size_t bytes) -> void* {
    void* p = ws + off;
    off += (bytes + 255) & ~(size_t)255;
    return p;
  };

  int2*     ed       = (int2*)alloc((size_t)NE * 8);          // CSR (src, w)
  int*      ppos     = (int*)alloc((size_t)NE * 4);           // per-edge sub-bucket position
  int*      cnt      = (int*)alloc((size_t)NSUB * NN * 4);    // sub-counts -> sub-offsets
  int*      tot      = (int*)alloc((size_t)NN * 4);
  int*      rowptr   = (int*)alloc(((size_t)NN + 1) * 4);
  int*      bsum     = (int*)alloc(512 * 4);
  int*      bpre     = (int*)alloc(512 * 4);
  float*    dinv     = (float*)alloc((size_t)NN * 4);
  float*    pA       = (float*)alloc((size_t)NN * 8 * 4);     // scalar use in layer1, 8-wide in layer2
  float*    pB       = (float*)alloc((size_t)NN * 8 * 4);
  float*    h1       = (float*)alloc((size_t)NN * 8 * 4);
  float*    g0       = (float*)alloc((size_t)NN * 4);
  float*    s1       = (float*)alloc((size_t)NN * 4);
  float*    s2       = (float*)alloc((size_t)NN * 4);
  float*    s3       = (float*)alloc((size_t)NN * 4);
  float*    u        = (float*)alloc((size_t)NN * 4);
  float*    v        = (float*)alloc((size_t)NN * 4);
  float*    h3       = (float*)alloc((size_t)NN * 4);
  float*    hn       = (float*)alloc((size_t)NN * 4);
  unsigned* key      = (unsigned*)alloc((size_t)NN * 4);
  double*   stats    = (double*)alloc(2 * 8);
  unsigned* hist     = (unsigned*)alloc(256 * 4);
  int*      partials = (int*)alloc(512 * 4);
  int*      offs     = (int*)alloc(512 * 4);
  unsigned* prefix   = (unsigned*)alloc(4);
  int*      target   = (int*)alloc(4);

  k_init<<<1, 1, 0, stream>>>(kptr, prefix, target, stats);

  // ---- build CSR by dst: 4-way sub-count, totals, scan, scatter (no atomics) ----
  hipMemsetAsync(cnt, 0, (size_t)NSUB * NN * 4, stream);
  k_cnt<<<GRID_E, TPB, 0, stream>>>(dst, cnt, ppos);
  k_tot<<<GRID_N, TPB, 0, stream>>>(cnt, tot);
  k_bsum<<<GRID_N, TPB, 0, stream>>>(tot, bsum);
  k_bscan<<<1, 64, 0, stream>>>(bsum, bpre, rowptr);
  k_rowptr<<<GRID_N, TPB, 0, stream>>>(tot, bpre, rowptr);
  k_scatter<<<GRID_E, TPB, 0, stream>>>(src, dst, ea, ppos, rowptr, cnt, ed);

  // ---- weighted degree + dinv from CSR ----
  g_degdinv<<<GRID_N4, TPB, 0, stream>>>(rowptr, ed, dinv);

  // ---- layer 1 (F=1): prop+normfix, prop, prop+combine1 -> h1 ----
  g_prop1fix<<<GRID_N4, TPB, 0, stream>>>(rowptr, ed, dinv, x, pA);
  g_prop1<<<GRID_N4, TPB, 0, stream>>>(rowptr, ed, pA, pB);
  g_prop1c<<<GRID_N4, TPB, 0, stream>>>(rowptr, ed, x, pA, pB, pB, W1, b1, h1);

  // ---- layer 2 (F=8): prop8, prop8, prop8+combine8+layer3-projection ----
  g_prop8<<<GRID_N4, TPB, 0, stream>>>(rowptr, ed, h1, pA);
  g_prop8<<<GRID_N4, TPB, 0, stream>>>(rowptr, ed, pA, pB);
  g_prop8l3<<<GRID_N4, TPB, 0, stream>>>(rowptr, ed, h1, pA, pB, W2, b2, W3, b3,
                                         g0, s1, s2, s3);

  // ---- layer 3 (scalar Horner): h3 = relu(g0 + S(s1 + S(s2 + S s3))) ----
  g_prop1add<0><<<GRID_N4, TPB, 0, stream>>>(rowptr, ed, s3, s2, u);
  g_prop1add<0><<<GRID_N4, TPB, 0, stream>>>(rowptr, ed, u, s1, v);
  g_prop1add<1><<<GRID_N4, TPB, 0, stream>>>(rowptr, ed, v, g0, h3);

  // ---- layernorm ----
  k_stats<<<GRID_N, TPB, 0, stream>>>(h3, stats);
  k_normkey<<<GRID_N, TPB, 0, stream>>>(h3, stats, hn, key);

  // ---- radix select: k-th largest ----
  hipMemsetAsync(hist, 0, 1024, stream);
  k_hist<24, 0x00000000u><<<GRID_N, TPB, 0, stream>>>(key, prefix, hist);
  k_pick<24><<<1, 1, 0, stream>>>(hist, prefix, target);
  hipMemsetAsync(hist, 0, 1024, stream);
  k_hist<16, 0xFF000000u><<<GRID_N, TPB, 0, stream>>>(key, prefix, hist);
  k_pick<16><<<1, 1, 0, stream>>>(hist, prefix, target);
  hipMemsetAsync(hist, 0, 1024, stream);
  k_hist<8, 0xFFFF0000u><<<GRID_N, TPB, 0, stream>>>(key, prefix, hist);
  k_pick<8><<<1, 1, 0, stream>>>(hist, prefix, target);
  hipMemsetAsync(hist, 0, 1024, stream);
  k_hist<0, 0xFFFFFF00u><<<GRID_N, TPB, 0, stream>>>(key, prefix, hist);
  k_pick<0><<<1, 1, 0, stream>>>(hist, prefix, target);

  // ---- stable membership + output (r = target after pass 4) ----
  k_count<<<GRID_N, TPB, 0, stream>>>(key, prefix, partials);
  k_scan<<<1, 64, 0, stream>>>(partials, offs);
  k_final<<<GRID_N, TPB, 0, stream>>>(hn, key, prefix, offs, target, out);
}

// Round 7
// 574.401 us; speedup vs baseline: 14.9681x; 1.1666x over previous
//
#include <hip/hip_runtime.h>
#include <math.h>

#define NN 100000
#define NE 3200000
#define NBKT 782        // ceil(NN/128) buckets of 128 nodes
#define NBLK 196        // histogram/scatter blocks
#define EPB 16384       // edges per block (196*16384 >= NE)
#define BCAP 6144       // per-bucket capacity (mean 4093, +32 sigma)

static constexpr int TPB = 256;
static constexpr int GRID_N = (NN + TPB - 1) / TPB;       // 391
static constexpr int GRID_N4 = (NN * 4 + TPB - 1) / TPB;  // 1563 (4 lanes per node)

// ---------------- init small state ----------------
__global__ void k_init(const int* __restrict__ kptr, unsigned* __restrict__ prefix,
                       int* __restrict__ target, double* __restrict__ stats) {
  *prefix = 0u;
  *target = *kptr;
  stats[0] = 0.0;
  stats[1] = 0.0;
}

// ---------------- K1: per-block LDS histogram over 782 buckets ----------------
__global__ void b_hist(const int* __restrict__ dst, int* __restrict__ histT) {
  __shared__ int h[NBKT];
  for (int i = threadIdx.x; i < NBKT; i += TPB) h[i] = 0;
  __syncthreads();
  int base = blockIdx.x * EPB;
  #pragma unroll 4
  for (int i = 0; i < EPB / TPB; ++i) {
    int e = base + i * TPB + threadIdx.x;
    if (e < NE) atomicAdd(&h[dst[e] >> 7], 1);
  }
  __syncthreads();
  for (int i = threadIdx.x; i < NBKT; i += TPB)
    histT[i * NBLK + blockIdx.x] = h[i];
}

// ---------------- K2a: exclusive scan of each bucket row (196 entries), in place ----------------
__global__ void b_rowscan(int* __restrict__ histT, int* __restrict__ rowsum) {
  int r = blockIdx.x, lane = threadIdx.x;   // 64 lanes
  int base = r * NBLK;
  int v[4]; int s = 0;
  #pragma unroll
  for (int i = 0; i < 4; ++i) {
    int c = lane * 4 + i;
    v[i] = (c < NBLK) ? histT[base + c] : 0;
    s += v[i];
  }
  int pre = s;
  for (int off = 1; off < 64; off <<= 1) {
    int t = __shfl_up(pre, off);
    if (lane >= off) pre += t;
  }
  int excl = pre - s;
  #pragma unroll
  for (int i = 0; i < 4; ++i) {
    int c = lane * 4 + i;
    if (c < NBLK) histT[base + c] = excl;
    excl += v[i];
  }
  if (lane == 63) rowsum[r] = pre;
}

// ---------------- K2b: bucket bases ----------------
__global__ void b_base(const int* __restrict__ rowsum, int* __restrict__ bucketBase,
                       int* __restrict__ rowptr) {
  if (threadIdx.x == 0) {
    int acc = 0;
    for (int b = 0; b < NBKT; ++b) { bucketBase[b] = acc; acc += rowsum[b]; }
    bucketBase[NBKT] = NE;
    rowptr[NN] = NE;
  }
}

// ---------------- K3: scatter edges grouped by bucket (LDS cursors, no global atomics) ----------------
__global__ void b_scatter(const int* __restrict__ src, const int* __restrict__ dst,
                          const float* __restrict__ ea, const int* __restrict__ histT,
                          const int* __restrict__ bucketBase, int2* __restrict__ grouped) {
  __shared__ int cursor[NBKT];
  for (int b = threadIdx.x; b < NBKT; b += TPB)
    cursor[b] = bucketBase[b] + histT[b * NBLK + blockIdx.x];
  __syncthreads();
  int base = blockIdx.x * EPB;
  #pragma unroll 4
  for (int i = 0; i < EPB / TPB; ++i) {
    int e = base + i * TPB + threadIdx.x;
    if (e < NE) {
      int d = dst[e];
      int pos = atomicAdd(&cursor[d >> 7], 1);
      int meta = ((d & 127) << 17) | src[e];
      grouped[pos] = make_int2(meta, __float_as_int(fabsf(ea[e])));
    }
  }
}

// ---------------- K4: per-bucket LDS counting sort + rowptr + weighted deg/dinv ----------------
__global__ void __launch_bounds__(512) b_sortdeg(const int* __restrict__ bucketBase,
                                                 const int2* __restrict__ grouped,
                                                 int2* __restrict__ ed, int* __restrict__ rowptr,
                                                 float* __restrict__ dinv) {
  __shared__ int hist[128];
  __shared__ float degf[128];
  __shared__ int binoff[128];
  __shared__ int cursor[128];
  __shared__ int2 out[BCAP];
  int b = blockIdx.x, t = threadIdx.x;
  int base = bucketBase[b], n = bucketBase[b + 1] - base;
  if (t < 128) { hist[t] = 0; degf[t] = 0.0f; }
  __syncthreads();
  for (int j = t; j < n; j += 512) {
    int2 el = grouped[base + j];
    int dl = el.x >> 17;
    atomicAdd(&hist[dl], 1);
    atomicAdd(&degf[dl], __int_as_float(el.y));
  }
  __syncthreads();
  if (t == 0) {
    int acc = 0;
    for (int i = 0; i < 128; ++i) { binoff[i] = acc; acc += hist[i]; }
  }
  __syncthreads();
  if (t < 128) {
    cursor[t] = binoff[t];
    int node = b * 128 + t;
    if (node < NN) {
      rowptr[node] = base + binoff[t];
      float dg = degf[t];
      dinv[node] = (dg > 0.0f) ? (1.0f / sqrtf(dg)) : 0.0f;
    }
  }
  __syncthreads();
  for (int j = t; j < n; j += 512) {
    int2 el = grouped[base + j];
    int dl = el.x >> 17;
    int pos = atomicAdd(&cursor[dl], 1);
    if (pos < BCAP) out[pos] = el;
  }
  __syncthreads();
  for (int j = t; j < n; j += 512) {
    int2 el = out[j];
    ed[base + j] = make_int2(el.x & 0x1FFFF, el.y);
  }
}

// ---------------- scalar propagation kernels ----------------
// First prop fused with norm fix-up: rewrites ed.y = dinv[src]*|ea|*dinv[n].
__global__ void g_prop1fix(const int* __restrict__ rowptr, int2* __restrict__ ed,
                           const float* __restrict__ dinv, const float* __restrict__ hin,
                           float* __restrict__ hout) {
  int t = blockIdx.x * TPB + threadIdx.x;
  int n = t >> 2, r = t & 3;
  if (n >= NN) return;
  int s0 = rowptr[n], s1 = rowptr[n + 1];
  float dn = dinv[n];
  float acc = 0.0f;
  for (int i = s0 + r; i < s1; i += 4) {
    int2 e = ed[i];
    float w = __int_as_float(e.y) * dinv[e.x] * dn;
    ed[i].y = __float_as_int(w);
    acc += w * hin[e.x];
  }
  acc += __shfl_xor(acc, 1);
  acc += __shfl_xor(acc, 2);
  if (r == 0) hout[n] = acc;
}

__global__ void g_prop1(const int* __restrict__ rowptr, const int2* __restrict__ ed,
                        const float* __restrict__ hin, float* __restrict__ hout) {
  int t = blockIdx.x * TPB + threadIdx.x;
  int n = t >> 2, r = t & 3;
  if (n >= NN) return;
  int s0 = rowptr[n], s1 = rowptr[n + 1];
  float acc = 0.0f;
  for (int i = s0 + r; i < s1; i += 4) {
    int2 e = ed[i];
    acc += __int_as_float(e.y) * hin[e.x];
  }
  acc += __shfl_xor(acc, 1);
  acc += __shfl_xor(acc, 2);
  if (r == 0) hout[n] = acc;
}

// out[n] = addv[n] + S(gsrc)[n], optional relu (layer-3 Horner chain).
template <int RELU>
__global__ void g_prop1add(const int* __restrict__ rowptr, const int2* __restrict__ ed,
                           const float* __restrict__ gsrc, const float* __restrict__ addv,
                           float* __restrict__ out) {
  int t = blockIdx.x * TPB + threadIdx.x;
  int n = t >> 2, r = t & 3;
  if (n >= NN) return;
  int s0 = rowptr[n], s1 = rowptr[n + 1];
  float acc = 0.0f;
  for (int i = s0 + r; i < s1; i += 4) {
    int2 e = ed[i];
    acc += __int_as_float(e.y) * gsrc[e.x];
  }
  acc += __shfl_xor(acc, 1);
  acc += __shfl_xor(acc, 2);
  if (r == 0) {
    float v = addv[n] + acc;
    out[n] = RELU ? fmaxf(v, 0.0f) : v;
  }
}

// Third F=1 prop + fused combine1 -> h1 (8-wide).
__global__ void g_prop1c(const int* __restrict__ rowptr, const int2* __restrict__ ed,
                         const float* __restrict__ x, const float* __restrict__ p1,
                         const float* __restrict__ p2, const float* __restrict__ hin,
                         const float* __restrict__ W, const float* __restrict__ b,
                         float* __restrict__ out) {
  int t = blockIdx.x * TPB + threadIdx.x;
  int n = t >> 2, r = t & 3;
  if (n >= NN) return;
  int s0 = rowptr[n], s1 = rowptr[n + 1];
  float acc = 0.0f;
  for (int i = s0 + r; i < s1; i += 4) {
    int2 e = ed[i];
    acc += __int_as_float(e.y) * hin[e.x];
  }
  acc += __shfl_xor(acc, 1);
  acc += __shfl_xor(acc, 2);
  if (r == 0) {
    float h0 = x[n], h1 = p1[n], h2 = p2[n], h3 = acc;
    float* op = out + (size_t)n * 8;
    #pragma unroll
    for (int j = 0; j < 8; ++j) {
      float v = b[j] + h0 * W[j] + h1 * W[8 + j] + h2 * W[16 + j] + h3 * W[24 + j];
      op[j] = fmaxf(v, 0.0f);
    }
  }
}

// ---------------- 8-wide propagation ----------------
__global__ void g_prop8(const int* __restrict__ rowptr, const int2* __restrict__ ed,
                        const float* __restrict__ hin, float* __restrict__ hout) {
  int t = blockIdx.x * TPB + threadIdx.x;
  int n = t >> 2, r = t & 3;
  if (n >= NN) return;
  int s0 = rowptr[n], s1 = rowptr[n + 1];
  float a0 = 0, a1 = 0, a2 = 0, a3 = 0, a4 = 0, a5 = 0, a6 = 0, a7 = 0;
  for (int i = s0 + r; i < s1; i += 4) {
    int2 e = ed[i];
    float w = __int_as_float(e.y);
    const float4* hp = (const float4*)(hin + (size_t)e.x * 8);
    float4 xx = hp[0], yy = hp[1];
    a0 += w * xx.x; a1 += w * xx.y; a2 += w * xx.z; a3 += w * xx.w;
    a4 += w * yy.x; a5 += w * yy.y; a6 += w * yy.z; a7 += w * yy.w;
  }
  #pragma unroll
  for (int m = 1; m <= 2; m <<= 1) {
    a0 += __shfl_xor(a0, m); a1 += __shfl_xor(a1, m);
    a2 += __shfl_xor(a2, m); a3 += __shfl_xor(a3, m);
    a4 += __shfl_xor(a4, m); a5 += __shfl_xor(a5, m);
    a6 += __shfl_xor(a6, m); a7 += __shfl_xor(a7, m);
  }
  if (r == 0) {
    float4* op = (float4*)(hout + (size_t)n * 8);
    op[0] = make_float4(a0, a1, a2, a3);
    op[1] = make_float4(a4, a5, a6, a7);
  }
}

// Layer-2 final prop + fused combine8 (h2 in regs) + layer-3 scalar projections.
__global__ void g_prop8l3(const int* __restrict__ rowptr, const int2* __restrict__ ed,
                          const float* __restrict__ p0, const float* __restrict__ p1,
                          const float* __restrict__ hin,
                          const float* __restrict__ W2, const float* __restrict__ b2,
                          const float* __restrict__ W3, const float* __restrict__ b3,
                          float* __restrict__ g0o, float* __restrict__ s1o,
                          float* __restrict__ s2o, float* __restrict__ s3o) {
  int t = blockIdx.x * TPB + threadIdx.x;
  int n = t >> 2, r = t & 3;
  if (n >= NN) return;
  int s0 = rowptr[n], s1 = rowptr[n + 1];
  float a0 = 0, a1 = 0, a2 = 0, a3 = 0, a4 = 0, a5 = 0, a6 = 0, a7 = 0;
  for (int i = s0 + r; i < s1; i += 4) {
    int2 e = ed[i];
    float w = __int_as_float(e.y);
    const float4* hp = (const float4*)(hin + (size_t)e.x * 8);
    float4 xx = hp[0], yy = hp[1];
    a0 += w * xx.x; a1 += w * xx.y; a2 += w * xx.z; a3 += w * xx.w;
    a4 += w * yy.x; a5 += w * yy.y; a6 += w * yy.z; a7 += w * yy.w;
  }
  #pragma unroll
  for (int m = 1; m <= 2; m <<= 1) {
    a0 += __shfl_xor(a0, m); a1 += __shfl_xor(a1, m);
    a2 += __shfl_xor(a2, m); a3 += __shfl_xor(a3, m);
    a4 += __shfl_xor(a4, m); a5 += __shfl_xor(a5, m);
    a6 += __shfl_xor(a6, m); a7 += __shfl_xor(a7, m);
  }
  if (r == 0) {
    float h[4][8];
    const float4* hp = (const float4*)(p0 + (size_t)n * 8);
    float4 u = hp[0], v4 = hp[1];
    h[0][0]=u.x; h[0][1]=u.y; h[0][2]=u.z; h[0][3]=u.w; h[0][4]=v4.x; h[0][5]=v4.y; h[0][6]=v4.z; h[0][7]=v4.w;
    hp = (const float4*)(p1 + (size_t)n * 8);
    u = hp[0]; v4 = hp[1];
    h[1][0]=u.x; h[1][1]=u.y; h[1][2]=u.z; h[1][3]=u.w; h[1][4]=v4.x; h[1][5]=v4.y; h[1][6]=v4.z; h[1][7]=v4.w;
    hp = (const float4*)(hin + (size_t)n * 8);
    u = hp[0]; v4 = hp[1];
    h[2][0]=u.x; h[2][1]=u.y; h[2][2]=u.z; h[2][3]=u.w; h[2][4]=v4.x; h[2][5]=v4.y; h[2][6]=v4.z; h[2][7]=v4.w;
    h[3][0]=a0; h[3][1]=a1; h[3][2]=a2; h[3][3]=a3; h[3][4]=a4; h[3][5]=a5; h[3][6]=a6; h[3][7]=a7;
    float hv[8];
    #pragma unroll
    for (int j = 0; j < 8; ++j) {
      float v = b2[j];
      #pragma unroll
      for (int i = 0; i < 4; ++i) {
        #pragma unroll
        for (int f = 0; f < 8; ++f) v += h[i][f] * W2[i * 64 + f * 8 + j];
      }
      hv[j] = fmaxf(v, 0.0f);
    }
    float g0 = b3[0], sv1 = 0, sv2 = 0, sv3 = 0;
    #pragma unroll
    for (int f = 0; f < 8; ++f) {
      g0  += hv[f] * W3[f];
      sv1 += hv[f] * W3[8 + f];
      sv2 += hv[f] * W3[16 + f];
      sv3 += hv[f] * W3[24 + f];
    }
    g0o[n] = g0; s1o[n] = sv1; s2o[n] = sv2; s3o[n] = sv3;
  }
}

// ---------------- layernorm stats ----------------
__global__ void k_stats(const float* __restrict__ h, double* __restrict__ stats) {
  int n = blockIdx.x * TPB + threadIdx.x;
  float v = (n < NN) ? h[n] : 0.0f;
  double s = (double)v, s2 = (double)v * (double)v;
  #pragma unroll
  for (int o = 32; o > 0; o >>= 1) {
    s  += __shfl_down(s, o);
    s2 += __shfl_down(s2, o);
  }
  __shared__ double ls[4], ls2[4];
  int lane = threadIdx.x & 63, w = threadIdx.x >> 6;
  if (lane == 0) { ls[w] = s; ls2[w] = s2; }
  __syncthreads();
  if (threadIdx.x == 0) {
    atomicAdd(&stats[0], ls[0] + ls[1] + ls[2] + ls[3]);
    atomicAdd(&stats[1], ls2[0] + ls2[1] + ls2[2] + ls2[3]);
  }
}

__global__ void k_normkey(const float* __restrict__ h, const double* __restrict__ stats,
                          float* __restrict__ hn, unsigned* __restrict__ key) {
  int n = blockIdx.x * TPB + threadIdx.x;
  if (n >= NN) return;
  double mu = stats[0] / (double)NN;
  double var = stats[1] / (double)NN - mu * mu;
  if (var < 0.0) var = 0.0;
  double invs = 1.0 / sqrt(var + 1e-5);
  float v = (float)(((double)h[n] - mu) * invs);
  hn[n] = v;
  unsigned u = __float_as_uint(v);
  unsigned asc = (u & 0x80000000u) ? ~u : (u | 0x80000000u);
  key[n] = ~asc;
}

// ---------------- radix select (k-th largest) ----------------
template <int SHIFT, unsigned MASK>
__global__ void k_hist(const unsigned* __restrict__ key, const unsigned* __restrict__ prefix,
                       unsigned* __restrict__ hist) {
  __shared__ unsigned lh[256];
  lh[threadIdx.x] = 0;
  __syncthreads();
  int n = blockIdx.x * TPB + threadIdx.x;
  unsigned pfx = *prefix;
  if (n < NN) {
    unsigned kk = key[n];
    if ((kk & MASK) == pfx) atomicAdd(&lh[(kk >> SHIFT) & 0xffu], 1u);
  }
  __syncthreads();
  if (lh[threadIdx.x]) atomicAdd(&hist[threadIdx.x], lh[threadIdx.x]);
}

template <int SHIFT>
__global__ void k_pick(const unsigned* __restrict__ hist, unsigned* __restrict__ prefix,
                       int* __restrict__ target) {
  int t = *target;
  unsigned cum = 0;
  for (int b = 0; b < 256; ++b) {
    unsigned c = hist[b];
    if ((int)(cum + c) >= t) {
      *prefix |= ((unsigned)b) << SHIFT;
      *target = t - (int)cum;   // after last pass: rank within tied keys
      return;
    }
    cum += c;
  }
}

// ---------------- stable top-k membership ----------------
__global__ void k_count(const unsigned* __restrict__ key, const unsigned* __restrict__ prefix,
                        int* __restrict__ partials) {
  int n = blockIdx.x * TPB + threadIdx.x;
  unsigned T = *prefix;
  bool eq = (n < NN) && (key[n] == T);
  unsigned long long meq = __ballot(eq);
  __shared__ int ce[4];
  int lane = threadIdx.x & 63, w = threadIdx.x >> 6;
  if (lane == 0) ce[w] = __popcll(meq);
  __syncthreads();
  if (threadIdx.x == 0) partials[blockIdx.x] = ce[0] + ce[1] + ce[2] + ce[3];
}

__global__ void k_scan(const int* __restrict__ partials, int* __restrict__ offs) {
  if (threadIdx.x == 0) {
    int acc = 0;
    for (int b = 0; b < GRID_N; ++b) { offs[b] = acc; acc += partials[b]; }
  }
}

__global__ void k_final(const float* __restrict__ hn, const unsigned* __restrict__ key,
                        const unsigned* __restrict__ prefix, const int* __restrict__ offs,
                        const int* __restrict__ rptr, float* __restrict__ out) {
  int n = blockIdx.x * TPB + threadIdx.x;
  unsigned T = *prefix;
  int r = *rptr;
  bool eq = false, lt = false;
  float v = 0.0f;
  if (n < NN) {
    unsigned kk = key[n];
    eq = (kk == T);
    lt = (kk < T);
    v = hn[n];
  }
  unsigned long long m = __ballot(eq);
  __shared__ int wc[4];
  int lane = threadIdx.x & 63, w = threadIdx.x >> 6;
  if (lane == 0) wc[w] = __popcll(m);
  __syncthreads();
  int off = offs[blockIdx.x];
  for (int i = 0; i < w; ++i) off += wc[i];
  off += __popcll(m & ((1ull << lane) - 1ull));
  if (n >= NN) return;
  bool top = lt || (eq && off < r);
  unsigned asc = ~T;
  unsigned orig = (asc & 0x80000000u) ? (asc & 0x7fffffffu) : ~asc;
  float thr = fabsf(__uint_as_float(orig));
  float tkv = top ? 1.0f : -1.0f;
  float z = v - thr + tkv * 0.1f;
  out[2 * n]     = v;
  out[2 * n + 1] = 1.0f / (1.0f + expf(-z));
}

// ---------------- host launch ----------------
extern "C" void kernel_launch(void* const* d_in, const int* in_sizes, int n_in,
                              void* d_out, int out_size, void* d_ws, size_t ws_size,
                              hipStream_t stream) {
  const float* x       = (const float*)d_in[0];
  const float* ea      = (const float*)d_in[1];
  const float* W1      = (const float*)d_in[2];
  const float* b1      = (const float*)d_in[3];
  const float* W2      = (const float*)d_in[4];
  const float* b2      = (const float*)d_in[5];
  const float* W3      = (const float*)d_in[6];
  const float* b3      = (const float*)d_in[7];
  const int* ei        = (const int*)d_in[8];   // int32 on device
  const int* kptr      = (const int*)d_in[9];
  float* out           = (float*)d_out;

  const int* src = ei;        // row 0
  const int* dst = ei + NE;   // row 1

  char* ws = (char*)d_ws;
  size_t off = 0;
  auto alloc = [&](size_t bytes) -> void* {
    void* p = ws + off;
    off += (bytes + 255) & ~(size_t)255;
    return p;
  };

  int2*     ed       = (int2*)alloc((size_t)NE * 8);            // sorted CSR (src, w)
  int2*     grouped  = (int2*)alloc((size_t)NE * 8);            // bucket-grouped edges
  int*      histT    = (int*)alloc((size_t)NBKT * NBLK * 4);    // per-(bucket,block) counts
  int*      rowsum   = (int*)alloc((size_t)NBKT * 4);
  int*      bucketBase = (int*)alloc(((size_t)NBKT + 1) * 4);
  int*      rowptr   = (int*)alloc(((size_t)NN + 1) * 4);
  float*    dinv     = (float*)alloc((size_t)NN * 4);
  float*    pA       = (float*)alloc((size_t)NN * 8 * 4);
  float*    pB       = (float*)alloc((size_t)NN * 8 * 4);
  float*    h1       = (float*)alloc((size_t)NN * 8 * 4);
  float*    g0       = (float*)alloc((size_t)NN * 4);
  float*    s1       = (float*)alloc((size_t)NN * 4);
  float*    s2       = (float*)alloc((size_t)NN * 4);
  float*    s3       = (float*)alloc((size_t)NN * 4);
  float*    u        = (float*)alloc((size_t)NN * 4);
  float*    v        = (float*)alloc((size_t)NN * 4);
  float*    h3       = (float*)alloc((size_t)NN * 4);
  float*    hn       = (float*)alloc((size_t)NN * 4);
  unsigned* key      = (unsigned*)alloc((size_t)NN * 4);
  double*   stats    = (double*)alloc(2 * 8);
  unsigned* hist     = (unsigned*)alloc(256 * 4);
  int*      partials = (int*)alloc(512 * 4);
  int*      offs     = (int*)alloc(512 * 4);
  unsigned* prefix   = (unsigned*)alloc(4);
  int*      target   = (int*)alloc(4);

  k_init<<<1, 1, 0, stream>>>(kptr, prefix, target, stats);

  // ---- build sorted CSR: LDS histograms -> scan -> grouped scatter -> per-bucket sort ----
  b_hist<<<NBLK, TPB, 0, stream>>>(dst, histT);
  b_rowscan<<<NBKT, 64, 0, stream>>>(histT, rowsum);
  b_base<<<1, 64, 0, stream>>>(rowsum, bucketBase, rowptr);
  b_scatter<<<NBLK, TPB, 0, stream>>>(src, dst, ea, histT, bucketBase, grouped);
  b_sortdeg<<<NBKT, 512, 0, stream>>>(bucketBase, grouped, ed, rowptr, dinv);

  // ---- layer 1 (F=1): prop+normfix, prop, prop+combine1 -> h1 ----
  g_prop1fix<<<GRID_N4, TPB, 0, stream>>>(rowptr, ed, dinv, x, pA);
  g_prop1<<<GRID_N4, TPB, 0, stream>>>(rowptr, ed, pA, pB);
  g_prop1c<<<GRID_N4, TPB, 0, stream>>>(rowptr, ed, x, pA, pB, pB, W1, b1, h1);

  // ---- layer 2 (F=8): prop8, prop8, prop8+combine8+layer3-projection ----
  g_prop8<<<GRID_N4, TPB, 0, stream>>>(rowptr, ed, h1, pA);
  g_prop8<<<GRID_N4, TPB, 0, stream>>>(rowptr, ed, pA, pB);
  g_prop8l3<<<GRID_N4, TPB, 0, stream>>>(rowptr, ed, h1, pA, pB, W2, b2, W3, b3,
                                         g0, s1, s2, s3);

  // ---- layer 3 (scalar Horner): h3 = relu(g0 + S(s1 + S(s2 + S s3))) ----
  g_prop1add<0><<<GRID_N4, TPB, 0, stream>>>(rowptr, ed, s3, s2, u);
  g_prop1add<0><<<GRID_N4, TPB, 0, stream>>>(rowptr, ed, u, s1, v);
  g_prop1add<1><<<GRID_N4, TPB, 0, stream>>>(rowptr, ed, v, g0, h3);

  // ---- layernorm ----
  k_stats<<<GRID_N, TPB, 0, stream>>>(h3, stats);
  k_normkey<<<GRID_N, TPB, 0, stream>>>(h3, stats, hn, key);

  // ---- radix select: k-th largest ----
  hipMemsetAsync(hist, 0, 1024, stream);
  k_hist<24, 0x00000000u><<<GRID_N, TPB, 0, stream>>>(key, prefix, hist);
  k_pick<24><<<1, 1, 0, stream>>>(hist, prefix, target);
  hipMemsetAsync(hist, 0, 1024, stream);
  k_hist<16, 0xFF000000u><<<GRID_N, TPB, 0, stream>>>(key, prefix, hist);
  k_pick<16><<<1, 1, 0, stream>>>(hist, prefix, target);
  hipMemsetAsync(hist, 0, 1024, stream);
  k_hist<8, 0xFFFF0000u><<<GRID_N, TPB, 0, stream>>>(key, prefix, hist);
  k_pick<8><<<1, 1, 0, stream>>>(hist, prefix, target);
  hipMemsetAsync(hist, 0, 1024, stream);
  k_hist<0, 0xFFFFFF00u><<<GRID_N, TPB, 0, stream>>>(key, prefix, hist);
  k_pick<0><<<1, 1, 0, stream>>>(hist, prefix, target);

  // ---- stable membership + output ----
  k_count<<<GRID_N, TPB, 0, stream>>>(key, prefix, partials);
  k_scan<<<1, 64, 0, stream>>>(partials, offs);
  k_final<<<GRID_N, TPB, 0, stream>>>(hn, key, prefix, offs, target, out);
}